// Round 10
// baseline (600.906 us; speedup 1.0000x reference)
//
#include <hip/hip_runtime.h>
#include <math.h>

#define E_TOT 65536
#define B_G   128
#define QLD   1664   // fused buffer row: [S(128) | Q(512) | K(512) | VT(512)]
#define NCOL  1792   // GEMM cols: S|Q|K|VT (1664) + U(64) + VZ(4) + SZ(1) + pad(59, masked)

typedef __attribute__((ext_vector_type(8))) short short8;
typedef __attribute__((ext_vector_type(4))) short short4v;
typedef __attribute__((ext_vector_type(4))) float float4v;

__device__ __forceinline__ unsigned short f2bf(float f) {
    unsigned int u = __float_as_uint(f);
    unsigned int r = u + 0x7FFFu + ((u >> 16) & 1u);   // round-to-nearest-even
    return (unsigned short)(r >> 16);
}
__device__ __forceinline__ float bf2f(unsigned short h) {
    return __uint_as_float(((unsigned int)h) << 16);
}

// per-layer weight-prep pointer bundle (passed by value; uniform selects -> SGPRs)
struct LayerPrep {
    const float *Ws, *bs_, *Wq, *bq, *We, *Wv, *bv, *tW;
    float *Wst, *ws_z, *sbt, *zb, *Wu, *bu, *Wet, *wez, *Wvt, *bvt, *Wvz, *bvz;
    unsigned short *Whi, *Wlo;
    int Fin;
};

__device__ __forceinline__ LayerPrep pick(const LayerPrep& p0, const LayerPrep& p1,
                                          const LayerPrep& p2) {
    return blockIdx.y == 0 ? p0 : (blockIdx.y == 1 ? p1 : p2);
}

// ---------------- per-layer weight prep, lane-per-output (round-5 version, measured fast)
__global__ void prep_all_k(LayerPrep p0, LayerPrep p1, LayerPrep p2, const float* Wb0,
                           const float* Wb1, const float* Wb2) {
    LayerPrep p = pick(p0, p1, p2);
    const float* Wb = blockIdx.y == 0 ? Wb0 : (blockIdx.y == 1 ? Wb1 : Wb2);
    int Fin = p.Fin;
    int w = blockIdx.x * 4 + (threadIdx.x >> 6);
    int lane = threadIdx.x & 63;

    // ---- P1 unit map ----
    int U1 = Fin * 2;          // Wst
    int U2 = U1 + 2;           // sbt
    int U3 = U2 + Fin * 8;     // Wvt
    int U4 = U3 + 8;           // bvt
    int U5 = U4 + 128;         // Wet
    if (w < U5) {
        const float* A; const float* bp; float* outp; int R;
        if (w < U1) {
            int f = w >> 1, m0 = (w & 1) * 64;
            A = p.Ws + (size_t)f * 512; bp = p.tW + m0 + lane;
            outp = p.Wst + f * 128 + m0 + lane; R = 512;
        } else if (w < U2) {
            int m0 = (w - U1) * 64;
            A = p.bs_; bp = p.tW + m0 + lane;
            outp = p.sbt + m0 + lane; R = 512;
        } else if (w < U3) {
            int u = w - U2; int f = u >> 3, q = u & 7;
            int cb = (q >> 1) * 128, m0 = (q & 1) * 64;
            A = p.Wv + (size_t)f * 512 + cb; bp = p.tW + cb * 128 + m0 + lane;
            outp = p.Wvt + (size_t)f * 512 + q * 64 + lane; R = 128;
        } else if (w < U4) {
            int q = w - U3; int cb = (q >> 1) * 128, m0 = (q & 1) * 64;
            A = p.bv + cb; bp = p.tW + cb * 128 + m0 + lane;
            outp = p.bvt + q * 64 + lane; R = 128;
        } else {
            int u = w - U4; int j2 = u >> 1, m0 = (u & 1) * 64;
            int j = j2 & 15, cb = (j2 >> 4) * 128;
            A = p.We + j * 512 + cb; bp = p.tW + cb * 128 + m0 + lane;
            outp = p.Wet + j2 * 128 + m0 + lane; R = 128;
        }
        float a0 = 0.f, a1 = 0.f, a2 = 0.f, a3 = 0.f;
        for (int c = 0; c < R; c += 4) {
            a0 = fmaf(A[c],     bp[0],   a0);
            a1 = fmaf(A[c + 1], bp[128], a1);
            a2 = fmaf(A[c + 2], bp[256], a2);
            a3 = fmaf(A[c + 3], bp[384], a3);
            bp += 512;
        }
        *outp = (a0 + a1) + (a2 + a3);
        return;
    }

    // ---- P2 units ----
    int w2 = w - U5;
    int q1 = Fin, q2 = q1 + 1, q3 = q2 + Fin * 64, q4 = q3 + 64, q5 = q4 + 64;
    int q6 = q5 + Fin * 4, q7 = q6 + 4;
    if (w2 >= q7) return;
    float s = 0.f;
    if (w2 < q1) {
        int f = w2;
        for (int c = lane; c < 512; c += 64)
            s = fmaf(p.Ws[(size_t)f * 512 + c], Wb[512 + c] - Wb[1024 + c], s);
    } else if (w2 < q2) {
        for (int c = lane; c < 512; c += 64)
            s = fmaf(p.bs_[c], Wb[512 + c] - Wb[1024 + c], s);
    } else if (w2 < q3) {   // Wu
        int q = w2 - q2; int f = q >> 6; int j2 = q & 63;
        int j = j2 & 15; int cb = (j2 >> 4) * 128;
        s = p.Wq[(size_t)f * 512 + cb + lane] * p.We[j * 512 + cb + lane]
          + p.Wq[(size_t)f * 512 + cb + lane + 64] * p.We[j * 512 + cb + lane + 64];
    } else if (w2 < q4) {   // bu
        int j2 = w2 - q3; int j = j2 & 15; int cb = (j2 >> 4) * 128;
        s = p.bq[cb + lane] * p.We[j * 512 + cb + lane]
          + p.bq[cb + lane + 64] * p.We[j * 512 + cb + lane + 64];
    } else if (w2 < q5) {   // wez
        int j2 = w2 - q4; int j = j2 & 15; int cb = (j2 >> 4) * 128;
        s = p.We[j * 512 + cb + lane] * (Wb[cb + lane] + Wb[1024 + cb + lane])
          + p.We[j * 512 + cb + lane + 64] * (Wb[cb + lane + 64] + Wb[1024 + cb + lane + 64]);
    } else if (w2 < q6) {   // Wvz
        int q = w2 - q5; int f = q >> 2; int cb = (q & 3) * 128;
        s = p.Wv[(size_t)f * 512 + cb + lane] * (Wb[cb + lane] + Wb[1024 + cb + lane])
          + p.Wv[(size_t)f * 512 + cb + lane + 64] * (Wb[cb + lane + 64] + Wb[1024 + cb + lane + 64]);
    } else {                // bvz
        int cb = (w2 - q6) * 128;
        s = p.bv[cb + lane] * (Wb[cb + lane] + Wb[1024 + cb + lane])
          + p.bv[cb + lane + 64] * (Wb[cb + lane + 64] + Wb[1024 + cb + lane + 64]);
    }
#pragma unroll
    for (int off = 32; off; off >>= 1) s += __shfl_xor(s, off, 64);
    if (lane == 0) {
        if (w2 < q1) p.ws_z[w2] = s;
        else if (w2 < q2) p.zb[0] = s;
        else if (w2 < q3) p.Wu[w2 - q2] = s;
        else if (w2 < q4) p.bu[w2 - q3] = s;
        else if (w2 < q5) p.wez[w2 - q4] = s;
        else if (w2 < q6) p.Wvz[w2 - q5] = s;
        else p.bvz[w2 - q6] = s;
    }
}

// Wt[col][k] transposed+split from [Wst | Wq | Wk | Wvt | Wu | Wvz | ws_z | pad], 3 layers wide
__global__ void wsplit_all_k(LayerPrep p0, LayerPrep p1, LayerPrep p2,
                             const float* Wk0, const float* Wk1, const float* Wk2) {
    LayerPrep p = pick(p0, p1, p2);
    const float* Wk = blockIdx.y == 0 ? Wk0 : (blockIdx.y == 1 ? Wk1 : Wk2);
    int K = p.Fin, kshift = (K == 64) ? 6 : 7;
    int idx = blockIdx.x * 256 + threadIdx.x;
    if (idx >= NCOL * K) return;
    int col = idx >> kshift, k = idx & (K - 1);
    float w;
    if (col < 128)       w = p.Wst[k * 128 + col];
    else if (col < 640)  w = p.Wq[(size_t)k * 512 + col - 128];
    else if (col < 1152) w = Wk[(size_t)k * 512 + col - 640];
    else if (col < 1664) w = p.Wvt[(size_t)k * 512 + col - 1152];
    else if (col < 1728) w = p.Wu[(size_t)k * 64 + col - 1664];
    else if (col < 1732) w = p.Wvz[(size_t)k * 4 + col - 1728];
    else if (col == 1732) w = p.ws_z[k];
    else                 w = 0.f;
    unsigned short h = f2bf(w);
    p.Whi[idx] = h;
    p.Wlo[idx] = f2bf(w - bf2f(h));
}

// X split to bf16 hi/lo (only needed standalone for the fp32 network input x0)
__global__ void xsplit_k(const float* __restrict__ X, int total4,
                         unsigned short* __restrict__ Xhi, unsigned short* __restrict__ Xlo) {
    int idx = blockIdx.x * 256 + threadIdx.x;
    if (idx >= total4) return;
    float4 f = ((const float4*)X)[idx];
    unsigned short h0 = f2bf(f.x), h1 = f2bf(f.y), h2 = f2bf(f.z), h3 = f2bf(f.w);
    short4v hv = {(short)h0, (short)h1, (short)h2, (short)h3};
    short4v lv = {(short)f2bf(f.x - bf2f(h0)), (short)f2bf(f.y - bf2f(h1)),
                  (short)f2bf(f.z - bf2f(h2)), (short)f2bf(f.w - bf2f(h3))};
    *(short4v*)(Xhi + (size_t)idx * 4) = hv;
    *(short4v*)(Xlo + (size_t)idx * 4) = lv;
}

// ---------------- fused S/Q/K/VT/U/VZ/SZ GEMM via split-bf16 MFMA ----------------
// Round-7 structure (measured best): grid (28, N/128), 4 waves, 20 KB LDS, per-chunk
// LDS staging with next-chunk register prefetch (T14), LDS-transposed coalesced
// epilogue. Block (0,0) also zeroes the bn `stats` buffer (consumed by the following
// attn_combine_k, which now accumulates bn statistics; stream order guarantees safety).
template <int KT>
__global__ __launch_bounds__(256) void qkvs_mfma(
        const unsigned short* __restrict__ Xhi, const unsigned short* __restrict__ Xlo,
        const unsigned short* __restrict__ Whi, const unsigned short* __restrict__ Wlo,
        const float* __restrict__ bq, const float* __restrict__ bk,
        const float* __restrict__ bvt, const float* __restrict__ bu,
        const float* __restrict__ bvz, const float* __restrict__ zb,
        float* __restrict__ out, float* __restrict__ UB, float* __restrict__ VZB,
        float* __restrict__ SZB, int nwg8, float* __restrict__ statsZ) {
    constexpr int NKC = KT >> 5;            // 2 (K=64) or 4 (K=128)
    constexpr int NCH = KT >> 6;            // 1 or 2
    __shared__ __align__(16) unsigned short bs[2 * 64 * 80];   // 20 KB
    const int ldb = 80, loHalf = 64 * 80;
    int tid = threadIdx.x;
    int wave = tid >> 6, lane = tid & 63;
    int m = lane & 15, kg = lane >> 4;
    int hw = blockIdx.y * 28 + blockIdx.x;
    if (hw == 0) statsZ[tid] = 0.f;         // zero 256 floats for the fused bn-stats
    int lb = (hw & 7) * nwg8 + (hw >> 3);   // bijective (nwg % 8 == 0)
    int rowBase = (lb / 28) * 128;
    int n0 = rowBase + wave * 32;
    int c0 = (lb % 28) * 64;

    short8 ahi[2][NKC], alo[2][NKC];
#pragma unroll
    for (int rt = 0; rt < 2; ++rt) {
        const unsigned short* xh = Xhi + (size_t)(n0 + rt * 16 + m) * KT + kg * 8;
        const unsigned short* xl = Xlo + (size_t)(n0 + rt * 16 + m) * KT + kg * 8;
#pragma unroll
        for (int kc = 0; kc < NKC; ++kc) {
            ahi[rt][kc] = *(const short8*)(xh + kc * 32);
            alo[rt][kc] = *(const short8*)(xl + kc * 32);
        }
    }

    float4v acc[2][4];
#pragma unroll
    for (int rt = 0; rt < 2; ++rt)
#pragma unroll
        for (int ct = 0; ct < 4; ++ct) acc[rt][ct] = (float4v){0.f, 0.f, 0.f, 0.f};

    // stage registers: [buf][iter]  (2 iters of 256 threads cover 64 cols x 64 k)
    short8 ph[2][2], pl[2][2];
#pragma unroll
    for (int it = 0; it < 2; ++it) {
        int i = tid + it * 256; int col = i >> 3, part = i & 7;
        ph[0][it] = *(const short8*)(Whi + (size_t)(c0 + col) * KT + part * 8);
        pl[0][it] = *(const short8*)(Wlo + (size_t)(c0 + col) * KT + part * 8);
    }

#pragma unroll
    for (int ch = 0; ch < NCH; ++ch) {
        if (ch) __syncthreads();            // previous compute done reading bs
#pragma unroll
        for (int it = 0; it < 2; ++it) {
            int i = tid + it * 256; int col = i >> 3, part = i & 7;
            *(short8*)(bs + col * ldb + part * 8) = ph[ch & 1][it];
            *(short8*)(bs + loHalf + col * ldb + part * 8) = pl[ch & 1][it];
        }
        __syncthreads();
        if (ch + 1 < NCH) {                 // issue next chunk early (T14)
#pragma unroll
            for (int it = 0; it < 2; ++it) {
                int i = tid + it * 256; int col = i >> 3, part = i & 7;
                ph[(ch + 1) & 1][it] =
                    *(const short8*)(Whi + (size_t)(c0 + col) * KT + (ch + 1) * 64 + part * 8);
                pl[(ch + 1) & 1][it] =
                    *(const short8*)(Wlo + (size_t)(c0 + col) * KT + (ch + 1) * 64 + part * 8);
            }
        }
#pragma unroll
        for (int kc2 = 0; kc2 < 2; ++kc2) {
            const int kc = ch * 2 + kc2;    // compile-time constant after unroll
#pragma unroll
            for (int ct = 0; ct < 4; ++ct) {
                const unsigned short* bp = bs + (ct * 16 + m) * ldb + kg * 8 + kc2 * 32;
                short8 bhi = *(const short8*)(bp);
                short8 blo = *(const short8*)(bp + loHalf);
                acc[0][ct] = __builtin_amdgcn_mfma_f32_16x16x32_bf16(ahi[0][kc], bhi, acc[0][ct], 0, 0, 0);
                acc[0][ct] = __builtin_amdgcn_mfma_f32_16x16x32_bf16(alo[0][kc], bhi, acc[0][ct], 0, 0, 0);
                acc[0][ct] = __builtin_amdgcn_mfma_f32_16x16x32_bf16(ahi[0][kc], blo, acc[0][ct], 0, 0, 0);
                acc[1][ct] = __builtin_amdgcn_mfma_f32_16x16x32_bf16(ahi[1][kc], bhi, acc[1][ct], 0, 0, 0);
                acc[1][ct] = __builtin_amdgcn_mfma_f32_16x16x32_bf16(alo[1][kc], bhi, acc[1][ct], 0, 0, 0);
                acc[1][ct] = __builtin_amdgcn_mfma_f32_16x16x32_bf16(ahi[1][kc], blo, acc[1][ct], 0, 0, 0);
            }
        }
    }

    float bias[4];
#pragma unroll
    for (int ct = 0; ct < 4; ++ct) {
        int col = c0 + ct * 16 + m;
        float bv_;
        if (col < 128)       bv_ = 0.f;
        else if (col < 640)  bv_ = bq[col - 128];
        else if (col < 1152) bv_ = bk[col - 640];
        else if (col < 1664) bv_ = bvt[col - 1152];
        else if (col < 1728) bv_ = bu[col - 1664];
        else if (col < 1732) bv_ = bvz[col - 1728];
        else if (col == 1732) bv_ = zb[0];
        else                 bv_ = 0.f;
        bias[ct] = bv_;
    }

    if (c0 < 1664) {
        // ---- coalesced epilogue via LDS transpose (all 64 cols -> out) ----
        float* fs = (float*)bs;             // reuse; need 64*68*4 = 17408 B <= 20480
        const int lds_s = 68;               // 16B-aligned rows, 2-way bank aliasing (free)
#pragma unroll
        for (int rt = 0; rt < 2; ++rt) {
            __syncthreads();                // compute (rt=0) / prev read pass (rt=1) done
#pragma unroll
            for (int ct = 0; ct < 4; ++ct)
#pragma unroll
                for (int r = 0; r < 4; ++r) {
                    int row_l = wave * 16 + kg * 4 + r;     // 0..63
                    fs[row_l * lds_s + ct * 16 + m] = acc[rt][ct][r] + bias[ct];
                }
            __syncthreads();
            int ch4 = tid & 15;             // 16B chunk within the 256B row
            int rbase = tid >> 4;           // 0..15
#pragma unroll
            for (int it = 0; it < 4; ++it) {
                int rl = it * 16 + rbase;   // 0..63
                float4 v = *(const float4*)(fs + rl * lds_s + ch4 * 4);
                int row = rowBase + (rl >> 4) * 32 + rt * 16 + (rl & 15);
                *(float4*)(out + (size_t)row * QLD + c0 + ch4 * 4) = v;
            }
        }
    } else {
        // ---- scalar path for the U/VZ/SZ col-blocks (lb%28 == 26,27) ----
#pragma unroll
        for (int ct = 0; ct < 4; ++ct) {
            int col = c0 + ct * 16 + m;
            if (col > 1732) continue;
#pragma unroll
            for (int rt = 0; rt < 2; ++rt) {
#pragma unroll
                for (int r = 0; r < 4; ++r) {
                    int row = n0 + rt * 16 + kg * 4 + r;
                    float v = acc[rt][ct][r] + bias[ct];
                    if (col < 1728)      UB[(size_t)row * 64 + col - 1664] = v;
                    else if (col < 1732) VZB[(size_t)row * 4 + col - 1728] = v;
                    else                 SZB[row] = v;
                }
            }
        }
    }
}

// ---------------- per-graph CSR build (edges of graph g are [g*512,(g+1)*512)) --------------
__global__ __launch_bounds__(128) void csr_graph_k(const int* __restrict__ src,
                                                   const int* __restrict__ dst,
                                                   int* __restrict__ row_start,
                                                   int* __restrict__ row_end,
                                                   int* __restrict__ colb,
                                                   int* __restrict__ eidb) {
    __shared__ int cnt[128], pref[128], cur[128];
    int g = blockIdx.x, t = threadIdx.x;
    cnt[t] = 0;
    __syncthreads();
    int e0 = g * 512, nb = g * 128;
    int dl[4], sl[4];
#pragma unroll
    for (int i = 0; i < 4; ++i) {
        int e = e0 + t + i * 128;
        dl[i] = dst[e] - nb;
        sl[i] = src[e];
        atomicAdd(&cnt[dl[i]], 1);
    }
    __syncthreads();
    pref[t] = cnt[t];
    __syncthreads();
    for (int st = 1; st < 128; st <<= 1) {
        int v = (t >= st) ? pref[t - st] : 0;
        __syncthreads();
        pref[t] += v;
        __syncthreads();
    }
    int ex = pref[t] - cnt[t];
    row_start[nb + t] = e0 + ex;
    row_end[nb + t]   = e0 + pref[t];
    cur[t] = ex;
    __syncthreads();
#pragma unroll
    for (int i = 0; i < 4; ++i) {
        int pos = atomicAdd(&cur[dl[i]], 1);
        colb[e0 + pos] = sl[i];
        eidb[e0 + pos] = e0 + t + i * 128;
    }
}

// ---------------- attention + combine + t-layer epilogue + bn-stats, fully fused ----------
// Node-per-group layout (avg in-degree 4): wave = head, 16-lane group owns one node.
// After writing xn, each block pre-reduces its 512 xn values in LDS and issues 2 global
// atomics per channel -> replaces the separate bn_stats_k pass (stats zeroed by the
// preceding qkvs_mfma launch). XCD-swizzled block id.
__global__ __launch_bounds__(256) void attn_combine_k(
        const float* __restrict__ QB, const float* __restrict__ UB,
        const float* __restrict__ VZB, const float* __restrict__ SZB,
        const int* __restrict__ row_start, const int* __restrict__ row_end,
        const int* __restrict__ colb, const int* __restrict__ eidb,
        const float* __restrict__ ea, const float* __restrict__ wez,
        const float* __restrict__ Wet, const float* __restrict__ sbt,
        const float* __restrict__ tb, float* __restrict__ xn, int nwg8,
        float* __restrict__ stats) {
    __shared__ float shO[4][4][128];   // [nodeSlot][head][dim]  8 KB
    __shared__ float tsh[4][64];       // [nodeSlot][head*16+li] 1 KB
    __shared__ float zsh[4][4];
    __shared__ float ssum[2][128], ssq[2][128];   // bn partials, 2 KB
    int tid = threadIdx.x;
    int head = tid >> 6, lane = tid & 63;
    int grp = lane >> 4, li = lane & 15;
    int bid = blockIdx.x;
    int lb = (bid & 7) * nwg8 + (bid >> 3);   // bijective (grid % 8 == 0)
    int node = lb * 4 + grp;

    float wezv = wez[head * 16 + li];
    const float* Qr = QB + (size_t)node * QLD + 128 + head * 128 + li * 8;
    float4 q0 = *(const float4*)Qr;
    float4 q1 = *(const float4*)(Qr + 4);
    float uu = UB[(size_t)node * 64 + head * 16 + li];
    int beg = row_start[node], end = row_end[node];

    float l = 0.f, t = 0.f, zac = 0.f;
    float4 a0 = {0.f, 0.f, 0.f, 0.f}, a1 = {0.f, 0.f, 0.f, 0.f};
    const float scale = 0.08838834764831845f;  // 1/sqrt(128); alpha O(10), exp safe
    int j = beg;
    for (; j + 1 < end; j += 2) {              // 2 independent gathers in flight
        int s1 = colb[j],     e1 = eidb[j];
        int s2 = colb[j + 1], e2 = eidb[j + 1];
        const float* K1 = QB + (size_t)s1 * QLD + 640 + head * 128 + li * 8;
        const float* V1 = QB + (size_t)s1 * QLD + 1152 + head * 128 + li * 8;
        const float* K2 = QB + (size_t)s2 * QLD + 640 + head * 128 + li * 8;
        const float* V2 = QB + (size_t)s2 * QLD + 1152 + head * 128 + li * 8;
        float4 k10 = *(const float4*)K1, k11 = *(const float4*)(K1 + 4);
        float4 v10 = *(const float4*)V1, v11 = *(const float4*)(V1 + 4);
        float4 k20 = *(const float4*)K2, k21 = *(const float4*)(K2 + 4);
        float4 v20 = *(const float4*)V2, v21 = *(const float4*)(V2 + 4);
        float ea1 = ea[(size_t)e1 * 16 + li];
        float ea2 = ea[(size_t)e2 * 16 + li];
        float vz1 = VZB[(size_t)s1 * 4 + head];
        float vz2 = VZB[(size_t)s2 * 4 + head];
        float p1 = q0.x * k10.x + q0.y * k10.y + q0.z * k10.z + q0.w * k10.w
                 + q1.x * k11.x + q1.y * k11.y + q1.z * k11.z + q1.w * k11.w + ea1 * uu;
        float p2 = q0.x * k20.x + q0.y * k20.y + q0.z * k20.z + q0.w * k20.w
                 + q1.x * k21.x + q1.y * k21.y + q1.z * k21.z + q1.w * k21.w + ea2 * uu;
        p1 += __shfl_xor(p1, 1, 64); p1 += __shfl_xor(p1, 2, 64);
        p1 += __shfl_xor(p1, 4, 64); p1 += __shfl_xor(p1, 8, 64);
        p2 += __shfl_xor(p2, 1, 64); p2 += __shfl_xor(p2, 2, 64);
        p2 += __shfl_xor(p2, 4, 64); p2 += __shfl_xor(p2, 8, 64);
        float w1 = expf(p1 * scale), w2 = expf(p2 * scale);
        l += w1; l += w2;
        t = fmaf(w1, ea1, t); t = fmaf(w2, ea2, t);
        zac = fmaf(w1, vz1, zac); zac = fmaf(w2, vz2, zac);
        a0.x = fmaf(w1, v10.x, a0.x); a0.y = fmaf(w1, v10.y, a0.y);
        a0.z = fmaf(w1, v10.z, a0.z); a0.w = fmaf(w1, v10.w, a0.w);
        a1.x = fmaf(w1, v11.x, a1.x); a1.y = fmaf(w1, v11.y, a1.y);
        a1.z = fmaf(w1, v11.z, a1.z); a1.w = fmaf(w1, v11.w, a1.w);
        a0.x = fmaf(w2, v20.x, a0.x); a0.y = fmaf(w2, v20.y, a0.y);
        a0.z = fmaf(w2, v20.z, a0.z); a0.w = fmaf(w2, v20.w, a0.w);
        a1.x = fmaf(w2, v21.x, a1.x); a1.y = fmaf(w2, v21.y, a1.y);
        a1.z = fmaf(w2, v21.z, a1.z); a1.w = fmaf(w2, v21.w, a1.w);
    }
    if (j < end) {                              // tail edge
        int s1 = colb[j], e1 = eidb[j];
        const float* K1 = QB + (size_t)s1 * QLD + 640 + head * 128 + li * 8;
        const float* V1 = QB + (size_t)s1 * QLD + 1152 + head * 128 + li * 8;
        float4 k10 = *(const float4*)K1, k11 = *(const float4*)(K1 + 4);
        float4 v10 = *(const float4*)V1, v11 = *(const float4*)(V1 + 4);
        float ea1 = ea[(size_t)e1 * 16 + li];
        float vz1 = VZB[(size_t)s1 * 4 + head];
        float p1 = q0.x * k10.x + q0.y * k10.y + q0.z * k10.z + q0.w * k10.w
                 + q1.x * k11.x + q1.y * k11.y + q1.z * k11.z + q1.w * k11.w + ea1 * uu;
        p1 += __shfl_xor(p1, 1, 64); p1 += __shfl_xor(p1, 2, 64);
        p1 += __shfl_xor(p1, 4, 64); p1 += __shfl_xor(p1, 8, 64);
        float w1 = expf(p1 * scale);
        l += w1;
        t = fmaf(w1, ea1, t);
        zac = fmaf(w1, vz1, zac);
        a0.x = fmaf(w1, v10.x, a0.x); a0.y = fmaf(w1, v10.y, a0.y);
        a0.z = fmaf(w1, v10.z, a0.z); a0.w = fmaf(w1, v10.w, a0.w);
        a1.x = fmaf(w1, v11.x, a1.x); a1.y = fmaf(w1, v11.y, a1.y);
        a1.z = fmaf(w1, v11.z, a1.z); a1.w = fmaf(w1, v11.w, a1.w);
    }

    float inv = 1.f / (l + 1e-16f);
    float tn = t * inv;
    float zw = tn * wezv;
    zw += __shfl_xor(zw, 1, 64); zw += __shfl_xor(zw, 2, 64);
    zw += __shfl_xor(zw, 4, 64); zw += __shfl_xor(zw, 8, 64);
    float z = zac * inv + zw;

    float* op = &shO[grp][head][li * 8];
    op[0] = a0.x * inv; op[1] = a0.y * inv; op[2] = a0.z * inv; op[3] = a0.w * inv;
    op[4] = a1.x * inv; op[5] = a1.y * inv; op[6] = a1.z * inv; op[7] = a1.w * inv;
    tsh[grp][head * 16 + li] = tn;
    if (li == 0) zsh[grp][head] = z;
    __syncthreads();

    // epilogue: 512 outputs (4 nodes x 128 dims), 2 per thread sharing the Wet column
    int dim = tid & 127;
    int nsBase = tid >> 7;                     // 0 or 1; partner node is nsBase+2
    float sb = sbt[dim], tbv = tb[dim];
    float wet0 = 0.f, wet1 = 0.f;
#pragma unroll 8
    for (int jj = 0; jj < 64; ++jj) {
        float wv = Wet[jj * 128 + dim];
        wet0 = fmaf(tsh[nsBase][jj], wv, wet0);
        wet1 = fmaf(tsh[nsBase + 2][jj], wv, wet1);
    }
    float vout[2];
#pragma unroll
    for (int r = 0; r < 2; ++r) {
        int ns = nsBase + r * 2;
        float wet = r ? wet1 : wet0;
        int nd = lb * 4 + ns;
        float outT = shO[ns][0][dim] + shO[ns][1][dim] + shO[ns][2][dim] + shO[ns][3][dim] + wet;
        float zt = zsh[ns][0] + zsh[ns][1] + zsh[ns][2] + zsh[ns][3] + SZB[nd];
        float beta = 1.f / (1.f + expf(-zt));
        float S = QB[(size_t)nd * QLD + dim];
        float a = beta * (S + sb) + (1.f - beta) * outT + tbv;
        float v = fmaxf(a, 0.f);
        xn[(size_t)nd * 128 + dim] = v;
        vout[r] = v;
    }

    // fused bn-stats: pre-reduce the block's 4 nodes per channel, then 2 atomics
    ssum[nsBase][dim] = vout[0] + vout[1];
    ssq[nsBase][dim]  = vout[0] * vout[0] + vout[1] * vout[1];
    __syncthreads();
    if (tid < 128) {
        atomicAdd(&stats[dim], ssum[0][dim] + ssum[1][dim]);
        atomicAdd(&stats[128 + dim], ssq[0][dim] + ssq[1][dim]);
    }
}

// bn apply + emit bf16 hi/lo split for the next GEMM (fused xsplit).
// The fp32 x buffer is DEAD after this (next layer reads only Xhi/Xlo) -> no store.
__global__ void bn_apply_k(const float* __restrict__ x, int N, const float* __restrict__ stats,
                           const float* __restrict__ g, const float* __restrict__ b,
                           unsigned short* __restrict__ Xhi, unsigned short* __restrict__ Xlo) {
    int idx = blockIdx.x * blockDim.x + threadIdx.x;
    if (idx >= N * 128) return;
    int c = idx & 127;
    float m = stats[c] / (float)N;
    float var = fmaxf(stats[128 + c] / (float)N - m * m, 0.f);
    float inv = rsqrtf(var + 1e-5f);
    float v = g[c] * (x[idx] - m) * inv + b[c];
    unsigned short h = f2bf(v);
    Xhi[idx] = h;
    Xlo[idx] = f2bf(v - bf2f(h));
}

// bn apply + pooling score in one pass (wave = node). grid N/4, block 256.
__global__ void bn_apply_score_k(float* __restrict__ x, int N, const float* __restrict__ stats,
                                 const float* __restrict__ g, const float* __restrict__ b,
                                 const float* __restrict__ w, float* __restrict__ s) {
    int node = blockIdx.x * 4 + (threadIdx.x >> 6);
    int lane = threadIdx.x & 63;
    int c0 = lane, c1 = lane + 64;
    float m0 = stats[c0] / (float)N;
    float v0 = fmaxf(stats[128 + c0] / (float)N - m0 * m0, 0.f);
    float m1 = stats[c1] / (float)N;
    float v1 = fmaxf(stats[128 + c1] / (float)N - m1 * m1, 0.f);
    float* row = x + (size_t)node * 128;
    float x0 = g[c0] * (row[c0] - m0) * rsqrtf(v0 + 1e-5f) + b[c0];
    float x1 = g[c1] * (row[c1] - m1) * rsqrtf(v1 + 1e-5f) + b[c1];
    row[c0] = x0;
    row[c1] = x1;
    float w0 = w[c0], w1 = w[c1];
    float p  = x0 * w0 + x1 * w1;
    float nw = w0 * w0 + w1 * w1;
#pragma unroll
    for (int off = 32; off; off >>= 1) {
        p  += __shfl_xor(p, off, 64);
        nw += __shfl_xor(nw, off, 64);
    }
    if (lane == 0) s[node] = p / sqrtf(nw);
}

// ---------------- pool0: topk + gather + readout + CSR rebuild + bf16 split ----------------
// (xp fp32 gathered copy was dead — layer-2 consumes only Xhi/Xlo — removed.)
__global__ __launch_bounds__(128) void topk_pool0_k(
        const float* __restrict__ sc, const float* __restrict__ x,
        const int* __restrict__ src, const int* __restrict__ dst,
        float* __restrict__ rep,
        int* __restrict__ row_start, int* __restrict__ row_end,
        int* __restrict__ colb, int* __restrict__ eidb,
        unsigned short* __restrict__ Xhi, unsigned short* __restrict__ Xlo) {
    __shared__ float ls[128], th[64];
    __shared__ int lk[128], rk[128], oon[64];
    __shared__ int cnt[64], pref[64], cur[64];
    int g = blockIdx.x, t = threadIdx.x;
    float val = sc[g * 128 + t];
    ls[t] = val;
    __syncthreads();
    int c = 0;
    for (int j = 0; j < 128; ++j) {
        float vj = ls[j];
        c += (vj > val || (vj == val && j < t)) ? 1 : 0;
    }
    int kp = (c < 64) ? 1 : 0;
    lk[t] = kp;
    __syncthreads();
    int r = 0;
    for (int j = 0; j < t; ++j) r += lk[j];
    rk[t] = r;
    if (kp) { oon[r] = t; th[r] = tanhf(val); }
    __syncthreads();
    float mx = -INFINITY, sm = 0.f;
    for (int rr = 0; rr < 64; ++rr) {
        float v = x[(size_t)(g * 128 + oon[rr]) * 128 + t] * th[rr];
        int oidx = (g * 64 + rr) * 128 + t;
        unsigned short h = f2bf(v);
        Xhi[oidx] = h;
        Xlo[oidx] = f2bf(v - bf2f(h));
        mx = fmaxf(mx, v);
        sm += v;
    }
    rep[g * 256 + t] = mx;
    rep[g * 256 + 128 + t] = sm * (1.f / 64.f);
    if (t < 64) cnt[t] = 0;
    __syncthreads();
    int e0 = g * 512, nb = g * 128;
    int keepE[4], dr[4], sr[4];
#pragma unroll
    for (int i = 0; i < 4; ++i) {
        int e = e0 + t + i * 128;
        int s_ = src[e] - nb, d_ = dst[e] - nb;
        int ke = lk[s_] && lk[d_];
        keepE[i] = ke;
        dr[i] = rk[d_];
        sr[i] = rk[s_];
        if (ke) atomicAdd(&cnt[dr[i]], 1);
    }
    __syncthreads();
    if (t < 64) pref[t] = cnt[t];
    __syncthreads();
    for (int st = 1; st < 64; st <<= 1) {
        int v = (t < 64 && t >= st) ? pref[t - st] : 0;
        __syncthreads();
        if (t < 64) pref[t] += v;
        __syncthreads();
    }
    if (t < 64) {
        int ex = pref[t] - cnt[t];
        row_start[g * 64 + t] = e0 + ex;
        row_end[g * 64 + t]   = e0 + pref[t];
        cur[t] = ex;
    }
    __syncthreads();
#pragma unroll
    for (int i = 0; i < 4; ++i) {
        if (keepE[i]) {
            int pos = atomicAdd(&cur[dr[i]], 1);
            colb[e0 + pos] = g * 64 + sr[i];
            eidb[e0 + pos] = e0 + t + i * 128;
        }
    }
}

// ---------------- pool1: topk + readout only. n=64 -> k=32. block 128. ----------------------
__global__ __launch_bounds__(128) void topk_pool1_k(
        const float* __restrict__ sc, const float* __restrict__ x,
        float* __restrict__ rep) {
    __shared__ float ls[64], th[32];
    __shared__ int lk[64], oon[32];
    int g = blockIdx.x, t = threadIdx.x;
    float val = 0.f;
    if (t < 64) { val = sc[g * 64 + t]; ls[t] = val; }
    __syncthreads();
    if (t < 64) {
        int c = 0;
        for (int j = 0; j < 64; ++j) {
            float vj = ls[j];
            c += (vj > val || (vj == val && j < t)) ? 1 : 0;
        }
        int kp = (c < 32) ? 1 : 0;
        lk[t] = kp;
    }
    __syncthreads();
    if (t < 64 && lk[t]) {
        int r = 0;
        for (int j = 0; j < t; ++j) r += lk[j];
        oon[r] = t;
        th[r] = tanhf(val);
    }
    __syncthreads();
    float mx = -INFINITY, sm = 0.f;
    for (int rr = 0; rr < 32; ++rr) {
        float v = x[(size_t)(g * 64 + oon[rr]) * 128 + t] * th[rr];
        mx = fmaxf(mx, v);
        sm += v;
    }
    rep[g * 256 + t] = mx;
    rep[g * 256 + 128 + t] = sm * (1.f / 32.f);
}

// ---------------- MLP head: one block per graph, fp32 output ----------------
__global__ void head_k(const float* __restrict__ rep0, const float* __restrict__ rep1,
                       const float* __restrict__ W1, const float* __restrict__ b1,
                       const float* __restrict__ W2, const float* __restrict__ b2,
                       const float* __restrict__ W3, const float* __restrict__ b3,
                       float* __restrict__ out) {
    __shared__ float h[256], a1[256], a2[128], red[256];
    int g = blockIdx.x, t = threadIdx.x;  // 256
    h[t] = rep0[g * 256 + t] + rep1[g * 256 + t];
    __syncthreads();
    float acc = b1[t];
    for (int i = 0; i < 256; ++i) acc = fmaf(h[i], W1[i * 256 + t], acc);
    a1[t] = fmaxf(acc, 0.f);
    __syncthreads();
    if (t < 128) {
        float a = b2[t];
        for (int i = 0; i < 256; ++i) a = fmaf(a1[i], W2[i * 128 + t], a);
        a2[t] = fmaxf(a, 0.f);
    }
    __syncthreads();
    red[t] = (t < 128) ? a2[t] * W3[t] : 0.f;
    __syncthreads();
    for (int st = 128; st; st >>= 1) {
        if (t < st) red[t] += red[t + st];
        __syncthreads();
    }
    if (t == 0) out[g] = red[0] + b3[0];
}

// ======================================================================================
extern "C" void kernel_launch(void* const* d_in, const int* in_sizes, int n_in,
                              void* d_out, int out_size, void* d_ws, size_t ws_size,
                              hipStream_t stream) {
    (void)in_sizes; (void)n_in; (void)out_size; (void)ws_size;

    const float* x0    = (const float*)d_in[0];
    const int*   ei    = (const int*)d_in[1];
    const float* ea    = (const float*)d_in[2];
    const float* c1_Wq = (const float*)d_in[3];
    const float* c1_bq = (const float*)d_in[4];
    const float* c1_Wk = (const float*)d_in[5];
    const float* c1_bk = (const float*)d_in[6];
    const float* c1_Wv = (const float*)d_in[7];
    const float* c1_bv = (const float*)d_in[8];
    const float* c1_We = (const float*)d_in[9];
    const float* c1_Ws = (const float*)d_in[10];
    const float* c1_bs = (const float*)d_in[11];
    const float* c1_Wb = (const float*)d_in[12];
    const float* t1_W  = (const float*)d_in[13];
    const float* t1_b  = (const float*)d_in[14];
    const float* bn1_g = (const float*)d_in[15];
    const float* bn1_b = (const float*)d_in[16];
    const float* cl_Wq = (const float*)d_in[17];
    const float* cl_bq = (const float*)d_in[18];
    const float* cl_Wk = (const float*)d_in[19];
    const float* cl_bk = (const float*)d_in[20];
    const float* cl_Wv = (const float*)d_in[21];
    const float* cl_bv = (const float*)d_in[22];
    const float* cl_We = (const float*)d_in[23];
    const float* cl_Ws = (const float*)d_in[24];
    const float* cl_bs = (const float*)d_in[25];
    const float* cl_Wb = (const float*)d_in[26];
    const float* tl_W  = (const float*)d_in[27];
    const float* tl_b  = (const float*)d_in[28];
    const float* bnl_g = (const float*)d_in[29];
    const float* bnl_b = (const float*)d_in[30];
    const float* pool_w= (const float*)d_in[31];
    const float* l1_W  = (const float*)d_in[32];
    const float* l1_b  = (const float*)d_in[33];
    const float* l2_W  = (const float*)d_in[34];
    const float* l2_b  = (const float*)d_in[35];
    const float* l3_W  = (const float*)d_in[36];
    const float* l3_b  = (const float*)d_in[37];
    float* out = (float*)d_out;

    // -------- workspace layout (~138 MB) --------
    char* base = (char*)d_ws;
    size_t off = 0;
    auto alloc = [&](size_t bytes) -> void* {
        void* p = base + off;
        off += (bytes + 255) & ~(size_t)255;
        return p;
    };
    float* QB   = (float*)alloc((size_t)16384 * QLD * 4);   // 109 MB
    float* xA   = (float*)alloc((size_t)16384 * 128 * 4);
    float* xB   = (float*)alloc((size_t)16384 * 128 * 4);
    float* UB   = (float*)alloc((size_t)16384 * 64 * 4);
    float* VZB  = (float*)alloc((size_t)16384 * 4 * 4);
    float* SZB  = (float*)alloc((size_t)16384 * 4);
    float* stats  = (float*)alloc(256 * 4);
    float* scores = (float*)alloc(16384 * 4);
    float* rep0   = (float*)alloc(128 * 256 * 4);
    float* rep1   = (float*)alloc(128 * 256 * 4);
    int* row_start = (int*)alloc(16384 * 4);
    int* row_end   = (int*)alloc(16384 * 4);
    int* colb      = (int*)alloc(E_TOT * 4);
    int* eidb      = (int*)alloc(E_TOT * 4);
    unsigned short* Xhi = (unsigned short*)alloc((size_t)16384 * 128 * 2);  // 4.2 MB
    unsigned short* Xlo = (unsigned short*)alloc((size_t)16384 * 128 * 2);  // 4.2 MB

    // per-layer prep buffers
    LayerPrep P[3];
    const float* Wb_[3] = {c1_Wb, cl_Wb, cl_Wb + 1536};
    const float* Wk_[3] = {c1_Wk, cl_Wk, cl_Wk + 65536};
    for (int l = 0; l < 3; ++l) {
        LayerPrep& p = P[l];
        p.Wst  = (float*)alloc(128 * 128 * 4);
        p.ws_z = (float*)alloc(128 * 4);
        p.sbt  = (float*)alloc(128 * 4);
        p.zb   = (float*)alloc(16);
        p.Wu   = (float*)alloc(128 * 64 * 4);
        p.bu   = (float*)alloc(64 * 4);
        p.Wet  = (float*)alloc(64 * 128 * 4);
        p.wez  = (float*)alloc(64 * 4);
        p.Wvt  = (float*)alloc(128 * 512 * 4);
        p.bvt  = (float*)alloc(512 * 4);
        p.Wvz  = (float*)alloc(128 * 4 * 4);
        p.bvz  = (float*)alloc(16);
        p.Whi  = (unsigned short*)alloc((size_t)NCOL * 128 * 2);
        p.Wlo  = (unsigned short*)alloc((size_t)NCOL * 128 * 2);
    }
    P[0].Ws = c1_Ws; P[0].bs_ = c1_bs; P[0].Wq = c1_Wq; P[0].bq = c1_bq;
    P[0].We = c1_We; P[0].Wv = c1_Wv; P[0].bv = c1_bv; P[0].tW = t1_W; P[0].Fin = 64;
    P[1].Ws = cl_Ws; P[1].bs_ = cl_bs; P[1].Wq = cl_Wq; P[1].bq = cl_bq;
    P[1].We = cl_We; P[1].Wv = cl_Wv; P[1].bv = cl_bv; P[1].tW = tl_W; P[1].Fin = 128;
    P[2].Ws = cl_Ws + 65536; P[2].bs_ = cl_bs + 512; P[2].Wq = cl_Wq + 65536;
    P[2].bq = cl_bq + 512; P[2].We = cl_We + 8192; P[2].Wv = cl_Wv + 65536;
    P[2].bv = cl_bv + 512; P[2].tW = tl_W + 65536; P[2].Fin = 128;

    // ---- all weight prep up front, 3 layers wide (activation-independent) ----
    {
        int unitsMax = (10 * 128 + 138) + (69 * 128 + 133);
        prep_all_k<<<dim3((unitsMax + 3) / 4, 3), 256, 0, stream>>>(P[0], P[1], P[2],
                                                                    Wb_[0], Wb_[1], Wb_[2]);
        wsplit_all_k<<<dim3((NCOL * 128 + 255) / 256, 3), 256, 0, stream>>>(P[0], P[1], P[2],
                                                                            Wk_[0], Wk_[1], Wk_[2]);
    }

    // ---- CSR over original edges + input split ----
    csr_graph_k<<<B_G, 128, 0, stream>>>(ei, ei + E_TOT, row_start, row_end, colb, eidb);
    xsplit_k<<<(16384 * 64 / 4 + 255) / 256, 256, 0, stream>>>(x0, 16384 * 64 / 4, Xhi, Xlo);

    auto tconv = [&](int L, int N, const float* bq, const float* bk, const float* tb,
                     float* xn) {
        int nwg8 = 28 * (N / 128) / 8;
        if (P[L].Fin == 64)
            qkvs_mfma<64><<<dim3(28, N / 128), 256, 0, stream>>>(Xhi, Xlo, P[L].Whi, P[L].Wlo,
                                                                 bq, bk, P[L].bvt, P[L].bu,
                                                                 P[L].bvz, P[L].zb,
                                                                 QB, UB, VZB, SZB, nwg8, stats);
        else
            qkvs_mfma<128><<<dim3(28, N / 128), 256, 0, stream>>>(Xhi, Xlo, P[L].Whi, P[L].Wlo,
                                                                  bq, bk, P[L].bvt, P[L].bu,
                                                                  P[L].bvz, P[L].zb,
                                                                  QB, UB, VZB, SZB, nwg8, stats);
        attn_combine_k<<<N / 4, 256, 0, stream>>>(QB, UB, VZB, SZB,
                                                  row_start, row_end, colb, eidb,
                                                  ea, P[L].wez, P[L].Wet, P[L].sbt, tb,
                                                  xn, N / 32, stats);
    };

    // ---- layer 1: tconv(Fin=64) + t1 + bn1 (stats fused into attn) ----
    tconv(0, 16384, c1_bq, c1_bk, t1_b, xA);
    bn_apply_k<<<(16384 * 128 + 255) / 256, 256, 0, stream>>>(xA, 16384, stats, bn1_g, bn1_b,
                                                              Xhi, Xlo);

    // ---- loop layer 0 (Fin=128, N=16384) ----
    tconv(1, 16384, cl_bq, cl_bk, tl_b, xB);
    bn_apply_score_k<<<16384 / 4, 256, 0, stream>>>(xB, 16384, stats, bnl_g, bnl_b,
                                                    pool_w, scores);

    // ---- pool 0 (fused topk+gather+readout+CSR+split) ----
    topk_pool0_k<<<B_G, 128, 0, stream>>>(scores, xB, ei, ei + E_TOT, rep0,
                                          row_start, row_end, colb, eidb, Xhi, Xlo);

    // ---- loop layer 1 (Fin=128, N=8192) ----
    tconv(2, 8192, cl_bq + 512, cl_bk + 512, tl_b + 128, xB);
    bn_apply_score_k<<<8192 / 4, 256, 0, stream>>>(xB, 8192, stats, bnl_g + 128, bnl_b + 128,
                                                   pool_w + 128, scores);

    // ---- pool 1 (fused topk+readout) ----
    topk_pool1_k<<<B_G, 128, 0, stream>>>(scores, xB, rep1);

    // ---- MLP head (fp32 out) ----
    head_k<<<B_G, 256, 0, stream>>>(rep0, rep1, l1_W, l1_b, l2_W, l2_b, l3_W, l3_b, out);
}

// Round 11
// 480.100 us; speedup vs baseline: 1.2516x; 1.2516x over previous
//
#include <hip/hip_runtime.h>
#include <math.h>

#define E_TOT 65536
#define B_G   128
#define QLD   1664   // fused buffer row: [S(128) | Q(512) | K(512) | VT(512)]
#define NCOL  1792   // GEMM cols: S|Q|K|VT (1664) + U(64) + VZ(4) + SZ(1) + pad(59, masked)

typedef __attribute__((ext_vector_type(8))) short short8;
typedef __attribute__((ext_vector_type(4))) short short4v;
typedef __attribute__((ext_vector_type(4))) float float4v;

__device__ __forceinline__ unsigned short f2bf(float f) {
    unsigned int u = __float_as_uint(f);
    unsigned int r = u + 0x7FFFu + ((u >> 16) & 1u);   // round-to-nearest-even
    return (unsigned short)(r >> 16);
}
__device__ __forceinline__ float bf2f(unsigned short h) {
    return __uint_as_float(((unsigned int)h) << 16);
}

// per-layer weight-prep pointer bundle (passed by value; uniform selects -> SGPRs)
struct LayerPrep {
    const float *Ws, *bs_, *Wq, *bq, *We, *Wv, *bv, *tW;
    float *Wst, *ws_z, *sbt, *zb, *Wu, *bu, *Wet, *wez, *Wvt, *bvt, *Wvz, *bvz;
    unsigned short *Whi, *Wlo;
    int Fin;
};

__device__ __forceinline__ LayerPrep pick(const LayerPrep& p0, const LayerPrep& p1,
                                          const LayerPrep& p2) {
    return blockIdx.y == 0 ? p0 : (blockIdx.y == 1 ? p1 : p2);
}

// ---------------- per-layer weight prep, lane-per-output (round-5 version, measured fast)
__global__ void prep_all_k(LayerPrep p0, LayerPrep p1, LayerPrep p2, const float* Wb0,
                           const float* Wb1, const float* Wb2) {
    LayerPrep p = pick(p0, p1, p2);
    const float* Wb = blockIdx.y == 0 ? Wb0 : (blockIdx.y == 1 ? Wb1 : Wb2);
    int Fin = p.Fin;
    int w = blockIdx.x * 4 + (threadIdx.x >> 6);
    int lane = threadIdx.x & 63;

    // ---- P1 unit map ----
    int U1 = Fin * 2;          // Wst
    int U2 = U1 + 2;           // sbt
    int U3 = U2 + Fin * 8;     // Wvt
    int U4 = U3 + 8;           // bvt
    int U5 = U4 + 128;         // Wet
    if (w < U5) {
        const float* A; const float* bp; float* outp; int R;
        if (w < U1) {
            int f = w >> 1, m0 = (w & 1) * 64;
            A = p.Ws + (size_t)f * 512; bp = p.tW + m0 + lane;
            outp = p.Wst + f * 128 + m0 + lane; R = 512;
        } else if (w < U2) {
            int m0 = (w - U1) * 64;
            A = p.bs_; bp = p.tW + m0 + lane;
            outp = p.sbt + m0 + lane; R = 512;
        } else if (w < U3) {
            int u = w - U2; int f = u >> 3, q = u & 7;
            int cb = (q >> 1) * 128, m0 = (q & 1) * 64;
            A = p.Wv + (size_t)f * 512 + cb; bp = p.tW + cb * 128 + m0 + lane;
            outp = p.Wvt + (size_t)f * 512 + q * 64 + lane; R = 128;
        } else if (w < U4) {
            int q = w - U3; int cb = (q >> 1) * 128, m0 = (q & 1) * 64;
            A = p.bv + cb; bp = p.tW + cb * 128 + m0 + lane;
            outp = p.bvt + q * 64 + lane; R = 128;
        } else {
            int u = w - U4; int j2 = u >> 1, m0 = (u & 1) * 64;
            int j = j2 & 15, cb = (j2 >> 4) * 128;
            A = p.We + j * 512 + cb; bp = p.tW + cb * 128 + m0 + lane;
            outp = p.Wet + j2 * 128 + m0 + lane; R = 128;
        }
        float a0 = 0.f, a1 = 0.f, a2 = 0.f, a3 = 0.f;
        for (int c = 0; c < R; c += 4) {
            a0 = fmaf(A[c],     bp[0],   a0);
            a1 = fmaf(A[c + 1], bp[128], a1);
            a2 = fmaf(A[c + 2], bp[256], a2);
            a3 = fmaf(A[c + 3], bp[384], a3);
            bp += 512;
        }
        *outp = (a0 + a1) + (a2 + a3);
        return;
    }

    // ---- P2 units ----
    int w2 = w - U5;
    int q1 = Fin, q2 = q1 + 1, q3 = q2 + Fin * 64, q4 = q3 + 64, q5 = q4 + 64;
    int q6 = q5 + Fin * 4, q7 = q6 + 4;
    if (w2 >= q7) return;
    float s = 0.f;
    if (w2 < q1) {
        int f = w2;
        for (int c = lane; c < 512; c += 64)
            s = fmaf(p.Ws[(size_t)f * 512 + c], Wb[512 + c] - Wb[1024 + c], s);
    } else if (w2 < q2) {
        for (int c = lane; c < 512; c += 64)
            s = fmaf(p.bs_[c], Wb[512 + c] - Wb[1024 + c], s);
    } else if (w2 < q3) {   // Wu
        int q = w2 - q2; int f = q >> 6; int j2 = q & 63;
        int j = j2 & 15; int cb = (j2 >> 4) * 128;
        s = p.Wq[(size_t)f * 512 + cb + lane] * p.We[j * 512 + cb + lane]
          + p.Wq[(size_t)f * 512 + cb + lane + 64] * p.We[j * 512 + cb + lane + 64];
    } else if (w2 < q4) {   // bu
        int j2 = w2 - q3; int j = j2 & 15; int cb = (j2 >> 4) * 128;
        s = p.bq[cb + lane] * p.We[j * 512 + cb + lane]
          + p.bq[cb + lane + 64] * p.We[j * 512 + cb + lane + 64];
    } else if (w2 < q5) {   // wez
        int j2 = w2 - q4; int j = j2 & 15; int cb = (j2 >> 4) * 128;
        s = p.We[j * 512 + cb + lane] * (Wb[cb + lane] + Wb[1024 + cb + lane])
          + p.We[j * 512 + cb + lane + 64] * (Wb[cb + lane + 64] + Wb[1024 + cb + lane + 64]);
    } else if (w2 < q6) {   // Wvz
        int q = w2 - q5; int f = q >> 2; int cb = (q & 3) * 128;
        s = p.Wv[(size_t)f * 512 + cb + lane] * (Wb[cb + lane] + Wb[1024 + cb + lane])
          + p.Wv[(size_t)f * 512 + cb + lane + 64] * (Wb[cb + lane + 64] + Wb[1024 + cb + lane + 64]);
    } else {                // bvz
        int cb = (w2 - q6) * 128;
        s = p.bv[cb + lane] * (Wb[cb + lane] + Wb[1024 + cb + lane])
          + p.bv[cb + lane + 64] * (Wb[cb + lane + 64] + Wb[1024 + cb + lane + 64]);
    }
#pragma unroll
    for (int off = 32; off; off >>= 1) s += __shfl_xor(s, off, 64);
    if (lane == 0) {
        if (w2 < q1) p.ws_z[w2] = s;
        else if (w2 < q2) p.zb[0] = s;
        else if (w2 < q3) p.Wu[w2 - q2] = s;
        else if (w2 < q4) p.bu[w2 - q3] = s;
        else if (w2 < q5) p.wez[w2 - q4] = s;
        else if (w2 < q6) p.Wvz[w2 - q5] = s;
        else p.bvz[w2 - q6] = s;
    }
}

// Wt[col][k] transposed+split from [Wst | Wq | Wk | Wvt | Wu | Wvz | ws_z | pad], 3 layers wide
__global__ void wsplit_all_k(LayerPrep p0, LayerPrep p1, LayerPrep p2,
                             const float* Wk0, const float* Wk1, const float* Wk2) {
    LayerPrep p = pick(p0, p1, p2);
    const float* Wk = blockIdx.y == 0 ? Wk0 : (blockIdx.y == 1 ? Wk1 : Wk2);
    int K = p.Fin, kshift = (K == 64) ? 6 : 7;
    int idx = blockIdx.x * 256 + threadIdx.x;
    if (idx >= NCOL * K) return;
    int col = idx >> kshift, k = idx & (K - 1);
    float w;
    if (col < 128)       w = p.Wst[k * 128 + col];
    else if (col < 640)  w = p.Wq[(size_t)k * 512 + col - 128];
    else if (col < 1152) w = Wk[(size_t)k * 512 + col - 640];
    else if (col < 1664) w = p.Wvt[(size_t)k * 512 + col - 1152];
    else if (col < 1728) w = p.Wu[(size_t)k * 64 + col - 1664];
    else if (col < 1732) w = p.Wvz[(size_t)k * 4 + col - 1728];
    else if (col == 1732) w = p.ws_z[k];
    else                 w = 0.f;
    unsigned short h = f2bf(w);
    p.Whi[idx] = h;
    p.Wlo[idx] = f2bf(w - bf2f(h));
}

// X split to bf16 hi/lo (only needed standalone for the fp32 network input x0)
__global__ void xsplit_k(const float* __restrict__ X, int total4,
                         unsigned short* __restrict__ Xhi, unsigned short* __restrict__ Xlo) {
    int idx = blockIdx.x * 256 + threadIdx.x;
    if (idx >= total4) return;
    float4 f = ((const float4*)X)[idx];
    unsigned short h0 = f2bf(f.x), h1 = f2bf(f.y), h2 = f2bf(f.z), h3 = f2bf(f.w);
    short4v hv = {(short)h0, (short)h1, (short)h2, (short)h3};
    short4v lv = {(short)f2bf(f.x - bf2f(h0)), (short)f2bf(f.y - bf2f(h1)),
                  (short)f2bf(f.z - bf2f(h2)), (short)f2bf(f.w - bf2f(h3))};
    *(short4v*)(Xhi + (size_t)idx * 4) = hv;
    *(short4v*)(Xlo + (size_t)idx * 4) = lv;
}

// ---------------- fused S/Q/K/VT/U/VZ/SZ GEMM via split-bf16 MFMA ----------------
// Round-7 structure (measured best): grid (28, N/128), 4 waves, 20 KB LDS, per-chunk
// LDS staging with next-chunk register prefetch (T14), LDS-transposed coalesced epilogue.
template <int KT>
__global__ __launch_bounds__(256) void qkvs_mfma(
        const unsigned short* __restrict__ Xhi, const unsigned short* __restrict__ Xlo,
        const unsigned short* __restrict__ Whi, const unsigned short* __restrict__ Wlo,
        const float* __restrict__ bq, const float* __restrict__ bk,
        const float* __restrict__ bvt, const float* __restrict__ bu,
        const float* __restrict__ bvz, const float* __restrict__ zb,
        float* __restrict__ out, float* __restrict__ UB, float* __restrict__ VZB,
        float* __restrict__ SZB, int nwg8) {
    constexpr int NKC = KT >> 5;            // 2 (K=64) or 4 (K=128)
    constexpr int NCH = KT >> 6;            // 1 or 2
    __shared__ __align__(16) unsigned short bs[2 * 64 * 80];   // 20 KB
    const int ldb = 80, loHalf = 64 * 80;
    int tid = threadIdx.x;
    int wave = tid >> 6, lane = tid & 63;
    int m = lane & 15, kg = lane >> 4;
    int hw = blockIdx.y * 28 + blockIdx.x;
    int lb = (hw & 7) * nwg8 + (hw >> 3);   // bijective (nwg % 8 == 0)
    int rowBase = (lb / 28) * 128;
    int n0 = rowBase + wave * 32;
    int c0 = (lb % 28) * 64;

    short8 ahi[2][NKC], alo[2][NKC];
#pragma unroll
    for (int rt = 0; rt < 2; ++rt) {
        const unsigned short* xh = Xhi + (size_t)(n0 + rt * 16 + m) * KT + kg * 8;
        const unsigned short* xl = Xlo + (size_t)(n0 + rt * 16 + m) * KT + kg * 8;
#pragma unroll
        for (int kc = 0; kc < NKC; ++kc) {
            ahi[rt][kc] = *(const short8*)(xh + kc * 32);
            alo[rt][kc] = *(const short8*)(xl + kc * 32);
        }
    }

    float4v acc[2][4];
#pragma unroll
    for (int rt = 0; rt < 2; ++rt)
#pragma unroll
        for (int ct = 0; ct < 4; ++ct) acc[rt][ct] = (float4v){0.f, 0.f, 0.f, 0.f};

    // stage registers: [buf][iter]  (2 iters of 256 threads cover 64 cols x 64 k)
    short8 ph[2][2], pl[2][2];
#pragma unroll
    for (int it = 0; it < 2; ++it) {
        int i = tid + it * 256; int col = i >> 3, part = i & 7;
        ph[0][it] = *(const short8*)(Whi + (size_t)(c0 + col) * KT + part * 8);
        pl[0][it] = *(const short8*)(Wlo + (size_t)(c0 + col) * KT + part * 8);
    }

#pragma unroll
    for (int ch = 0; ch < NCH; ++ch) {
        if (ch) __syncthreads();            // previous compute done reading bs
#pragma unroll
        for (int it = 0; it < 2; ++it) {
            int i = tid + it * 256; int col = i >> 3, part = i & 7;
            *(short8*)(bs + col * ldb + part * 8) = ph[ch & 1][it];
            *(short8*)(bs + loHalf + col * ldb + part * 8) = pl[ch & 1][it];
        }
        __syncthreads();
        if (ch + 1 < NCH) {                 // issue next chunk early (T14)
#pragma unroll
            for (int it = 0; it < 2; ++it) {
                int i = tid + it * 256; int col = i >> 3, part = i & 7;
                ph[(ch + 1) & 1][it] =
                    *(const short8*)(Whi + (size_t)(c0 + col) * KT + (ch + 1) * 64 + part * 8);
                pl[(ch + 1) & 1][it] =
                    *(const short8*)(Wlo + (size_t)(c0 + col) * KT + (ch + 1) * 64 + part * 8);
            }
        }
#pragma unroll
        for (int kc2 = 0; kc2 < 2; ++kc2) {
            const int kc = ch * 2 + kc2;    // compile-time constant after unroll
#pragma unroll
            for (int ct = 0; ct < 4; ++ct) {
                const unsigned short* bp = bs + (ct * 16 + m) * ldb + kg * 8 + kc2 * 32;
                short8 bhi = *(const short8*)(bp);
                short8 blo = *(const short8*)(bp + loHalf);
                acc[0][ct] = __builtin_amdgcn_mfma_f32_16x16x32_bf16(ahi[0][kc], bhi, acc[0][ct], 0, 0, 0);
                acc[0][ct] = __builtin_amdgcn_mfma_f32_16x16x32_bf16(alo[0][kc], bhi, acc[0][ct], 0, 0, 0);
                acc[0][ct] = __builtin_amdgcn_mfma_f32_16x16x32_bf16(ahi[0][kc], blo, acc[0][ct], 0, 0, 0);
                acc[1][ct] = __builtin_amdgcn_mfma_f32_16x16x32_bf16(ahi[1][kc], bhi, acc[1][ct], 0, 0, 0);
                acc[1][ct] = __builtin_amdgcn_mfma_f32_16x16x32_bf16(alo[1][kc], bhi, acc[1][ct], 0, 0, 0);
                acc[1][ct] = __builtin_amdgcn_mfma_f32_16x16x32_bf16(ahi[1][kc], blo, acc[1][ct], 0, 0, 0);
            }
        }
    }

    float bias[4];
#pragma unroll
    for (int ct = 0; ct < 4; ++ct) {
        int col = c0 + ct * 16 + m;
        float bv_;
        if (col < 128)       bv_ = 0.f;
        else if (col < 640)  bv_ = bq[col - 128];
        else if (col < 1152) bv_ = bk[col - 640];
        else if (col < 1664) bv_ = bvt[col - 1152];
        else if (col < 1728) bv_ = bu[col - 1664];
        else if (col < 1732) bv_ = bvz[col - 1728];
        else if (col == 1732) bv_ = zb[0];
        else                 bv_ = 0.f;
        bias[ct] = bv_;
    }

    if (c0 < 1664) {
        // ---- coalesced epilogue via LDS transpose (all 64 cols -> out) ----
        float* fs = (float*)bs;             // reuse; need 64*68*4 = 17408 B <= 20480
        const int lds_s = 68;               // 16B-aligned rows, 2-way bank aliasing (free)
#pragma unroll
        for (int rt = 0; rt < 2; ++rt) {
            __syncthreads();                // compute (rt=0) / prev read pass (rt=1) done
#pragma unroll
            for (int ct = 0; ct < 4; ++ct)
#pragma unroll
                for (int r = 0; r < 4; ++r) {
                    int row_l = wave * 16 + kg * 4 + r;     // 0..63
                    fs[row_l * lds_s + ct * 16 + m] = acc[rt][ct][r] + bias[ct];
                }
            __syncthreads();
            int ch4 = tid & 15;             // 16B chunk within the 256B row
            int rbase = tid >> 4;           // 0..15
#pragma unroll
            for (int it = 0; it < 4; ++it) {
                int rl = it * 16 + rbase;   // 0..63
                float4 v = *(const float4*)(fs + rl * lds_s + ch4 * 4);
                int row = rowBase + (rl >> 4) * 32 + rt * 16 + (rl & 15);
                *(float4*)(out + (size_t)row * QLD + c0 + ch4 * 4) = v;
            }
        }
    } else {
        // ---- scalar path for the U/VZ/SZ col-blocks (lb%28 == 26,27) ----
#pragma unroll
        for (int ct = 0; ct < 4; ++ct) {
            int col = c0 + ct * 16 + m;
            if (col > 1732) continue;
#pragma unroll
            for (int rt = 0; rt < 2; ++rt) {
#pragma unroll
                for (int r = 0; r < 4; ++r) {
                    int row = n0 + rt * 16 + kg * 4 + r;
                    float v = acc[rt][ct][r] + bias[ct];
                    if (col < 1728)      UB[(size_t)row * 64 + col - 1664] = v;
                    else if (col < 1732) VZB[(size_t)row * 4 + col - 1728] = v;
                    else                 SZB[row] = v;
                }
            }
        }
    }
}

// ---------------- per-graph CSR build (edges of graph g are [g*512,(g+1)*512)) --------------
__global__ __launch_bounds__(128) void csr_graph_k(const int* __restrict__ src,
                                                   const int* __restrict__ dst,
                                                   int* __restrict__ row_start,
                                                   int* __restrict__ row_end,
                                                   int* __restrict__ colb,
                                                   int* __restrict__ eidb) {
    __shared__ int cnt[128], pref[128], cur[128];
    int g = blockIdx.x, t = threadIdx.x;
    cnt[t] = 0;
    __syncthreads();
    int e0 = g * 512, nb = g * 128;
    int dl[4], sl[4];
#pragma unroll
    for (int i = 0; i < 4; ++i) {
        int e = e0 + t + i * 128;
        dl[i] = dst[e] - nb;
        sl[i] = src[e];
        atomicAdd(&cnt[dl[i]], 1);
    }
    __syncthreads();
    pref[t] = cnt[t];
    __syncthreads();
    for (int st = 1; st < 128; st <<= 1) {
        int v = (t >= st) ? pref[t - st] : 0;
        __syncthreads();
        pref[t] += v;
        __syncthreads();
    }
    int ex = pref[t] - cnt[t];
    row_start[nb + t] = e0 + ex;
    row_end[nb + t]   = e0 + pref[t];
    cur[t] = ex;
    __syncthreads();
#pragma unroll
    for (int i = 0; i < 4; ++i) {
        int pos = atomicAdd(&cur[dl[i]], 1);
        colb[e0 + pos] = sl[i];
        eidb[e0 + pos] = e0 + t + i * 128;
    }
}

// ---------------- attention + combine + t-layer epilogue, fully fused ----------------
// Node-per-group layout (avg in-degree 4): wave = head, 16-lane group owns one node.
// ONE barrier per block; epilogue for 4 nodes on all 256 threads. XCD-swizzled block id.
// Block 0 zeroes the bn `stats` buffer (consumed by the following bn_stats_k pass;
// the fused-atomics variant measured 85 µs of contention — reverted).
__global__ __launch_bounds__(256) void attn_combine_k(
        const float* __restrict__ QB, const float* __restrict__ UB,
        const float* __restrict__ VZB, const float* __restrict__ SZB,
        const int* __restrict__ row_start, const int* __restrict__ row_end,
        const int* __restrict__ colb, const int* __restrict__ eidb,
        const float* __restrict__ ea, const float* __restrict__ wez,
        const float* __restrict__ Wet, const float* __restrict__ sbt,
        const float* __restrict__ tb, float* __restrict__ xn, int nwg8,
        float* __restrict__ statsZ) {
    __shared__ float shO[4][4][128];   // [nodeSlot][head][dim]  8 KB
    __shared__ float tsh[4][64];       // [nodeSlot][head*16+li] 1 KB
    __shared__ float zsh[4][4];
    int tid = threadIdx.x;
    int head = tid >> 6, lane = tid & 63;
    int grp = lane >> 4, li = lane & 15;
    int bid = blockIdx.x;
    if (bid == 0) statsZ[tid] = 0.f;          // 256 floats; consumed by bn_stats later
    int lb = (bid & 7) * nwg8 + (bid >> 3);   // bijective (grid % 8 == 0)
    int node = lb * 4 + grp;

    float wezv = wez[head * 16 + li];
    const float* Qr = QB + (size_t)node * QLD + 128 + head * 128 + li * 8;
    float4 q0 = *(const float4*)Qr;
    float4 q1 = *(const float4*)(Qr + 4);
    float uu = UB[(size_t)node * 64 + head * 16 + li];
    int beg = row_start[node], end = row_end[node];

    float l = 0.f, t = 0.f, zac = 0.f;
    float4 a0 = {0.f, 0.f, 0.f, 0.f}, a1 = {0.f, 0.f, 0.f, 0.f};
    const float scale = 0.08838834764831845f;  // 1/sqrt(128); alpha O(10), exp safe
    int j = beg;
    for (; j + 1 < end; j += 2) {              // 2 independent gathers in flight
        int s1 = colb[j],     e1 = eidb[j];
        int s2 = colb[j + 1], e2 = eidb[j + 1];
        const float* K1 = QB + (size_t)s1 * QLD + 640 + head * 128 + li * 8;
        const float* V1 = QB + (size_t)s1 * QLD + 1152 + head * 128 + li * 8;
        const float* K2 = QB + (size_t)s2 * QLD + 640 + head * 128 + li * 8;
        const float* V2 = QB + (size_t)s2 * QLD + 1152 + head * 128 + li * 8;
        float4 k10 = *(const float4*)K1, k11 = *(const float4*)(K1 + 4);
        float4 v10 = *(const float4*)V1, v11 = *(const float4*)(V1 + 4);
        float4 k20 = *(const float4*)K2, k21 = *(const float4*)(K2 + 4);
        float4 v20 = *(const float4*)V2, v21 = *(const float4*)(V2 + 4);
        float ea1 = ea[(size_t)e1 * 16 + li];
        float ea2 = ea[(size_t)e2 * 16 + li];
        float vz1 = VZB[(size_t)s1 * 4 + head];
        float vz2 = VZB[(size_t)s2 * 4 + head];
        float p1 = q0.x * k10.x + q0.y * k10.y + q0.z * k10.z + q0.w * k10.w
                 + q1.x * k11.x + q1.y * k11.y + q1.z * k11.z + q1.w * k11.w + ea1 * uu;
        float p2 = q0.x * k20.x + q0.y * k20.y + q0.z * k20.z + q0.w * k20.w
                 + q1.x * k21.x + q1.y * k21.y + q1.z * k21.z + q1.w * k21.w + ea2 * uu;
        p1 += __shfl_xor(p1, 1, 64); p1 += __shfl_xor(p1, 2, 64);
        p1 += __shfl_xor(p1, 4, 64); p1 += __shfl_xor(p1, 8, 64);
        p2 += __shfl_xor(p2, 1, 64); p2 += __shfl_xor(p2, 2, 64);
        p2 += __shfl_xor(p2, 4, 64); p2 += __shfl_xor(p2, 8, 64);
        float w1 = expf(p1 * scale), w2 = expf(p2 * scale);
        l += w1; l += w2;
        t = fmaf(w1, ea1, t); t = fmaf(w2, ea2, t);
        zac = fmaf(w1, vz1, zac); zac = fmaf(w2, vz2, zac);
        a0.x = fmaf(w1, v10.x, a0.x); a0.y = fmaf(w1, v10.y, a0.y);
        a0.z = fmaf(w1, v10.z, a0.z); a0.w = fmaf(w1, v10.w, a0.w);
        a1.x = fmaf(w1, v11.x, a1.x); a1.y = fmaf(w1, v11.y, a1.y);
        a1.z = fmaf(w1, v11.z, a1.z); a1.w = fmaf(w1, v11.w, a1.w);
        a0.x = fmaf(w2, v20.x, a0.x); a0.y = fmaf(w2, v20.y, a0.y);
        a0.z = fmaf(w2, v20.z, a0.z); a0.w = fmaf(w2, v20.w, a0.w);
        a1.x = fmaf(w2, v21.x, a1.x); a1.y = fmaf(w2, v21.y, a1.y);
        a1.z = fmaf(w2, v21.z, a1.z); a1.w = fmaf(w2, v21.w, a1.w);
    }
    if (j < end) {                              // tail edge
        int s1 = colb[j], e1 = eidb[j];
        const float* K1 = QB + (size_t)s1 * QLD + 640 + head * 128 + li * 8;
        const float* V1 = QB + (size_t)s1 * QLD + 1152 + head * 128 + li * 8;
        float4 k10 = *(const float4*)K1, k11 = *(const float4*)(K1 + 4);
        float4 v10 = *(const float4*)V1, v11 = *(const float4*)(V1 + 4);
        float ea1 = ea[(size_t)e1 * 16 + li];
        float vz1 = VZB[(size_t)s1 * 4 + head];
        float p1 = q0.x * k10.x + q0.y * k10.y + q0.z * k10.z + q0.w * k10.w
                 + q1.x * k11.x + q1.y * k11.y + q1.z * k11.z + q1.w * k11.w + ea1 * uu;
        p1 += __shfl_xor(p1, 1, 64); p1 += __shfl_xor(p1, 2, 64);
        p1 += __shfl_xor(p1, 4, 64); p1 += __shfl_xor(p1, 8, 64);
        float w1 = expf(p1 * scale);
        l += w1;
        t = fmaf(w1, ea1, t);
        zac = fmaf(w1, vz1, zac);
        a0.x = fmaf(w1, v10.x, a0.x); a0.y = fmaf(w1, v10.y, a0.y);
        a0.z = fmaf(w1, v10.z, a0.z); a0.w = fmaf(w1, v10.w, a0.w);
        a1.x = fmaf(w1, v11.x, a1.x); a1.y = fmaf(w1, v11.y, a1.y);
        a1.z = fmaf(w1, v11.z, a1.z); a1.w = fmaf(w1, v11.w, a1.w);
    }

    float inv = 1.f / (l + 1e-16f);
    float tn = t * inv;
    float zw = tn * wezv;
    zw += __shfl_xor(zw, 1, 64); zw += __shfl_xor(zw, 2, 64);
    zw += __shfl_xor(zw, 4, 64); zw += __shfl_xor(zw, 8, 64);
    float z = zac * inv + zw;

    float* op = &shO[grp][head][li * 8];
    op[0] = a0.x * inv; op[1] = a0.y * inv; op[2] = a0.z * inv; op[3] = a0.w * inv;
    op[4] = a1.x * inv; op[5] = a1.y * inv; op[6] = a1.z * inv; op[7] = a1.w * inv;
    tsh[grp][head * 16 + li] = tn;
    if (li == 0) zsh[grp][head] = z;
    __syncthreads();

    // epilogue: 512 outputs (4 nodes x 128 dims), 2 per thread sharing the Wet column
    int dim = tid & 127;
    int nsBase = tid >> 7;                     // 0 or 1; partner node is nsBase+2
    float sb = sbt[dim], tbv = tb[dim];
    float wet0 = 0.f, wet1 = 0.f;
#pragma unroll 8
    for (int jj = 0; jj < 64; ++jj) {
        float wv = Wet[jj * 128 + dim];
        wet0 = fmaf(tsh[nsBase][jj], wv, wet0);
        wet1 = fmaf(tsh[nsBase + 2][jj], wv, wet1);
    }
#pragma unroll
    for (int r = 0; r < 2; ++r) {
        int ns = nsBase + r * 2;
        float wet = r ? wet1 : wet0;
        int nd = lb * 4 + ns;
        float outT = shO[ns][0][dim] + shO[ns][1][dim] + shO[ns][2][dim] + shO[ns][3][dim] + wet;
        float zt = zsh[ns][0] + zsh[ns][1] + zsh[ns][2] + zsh[ns][3] + SZB[nd];
        float beta = 1.f / (1.f + expf(-zt));
        float S = QB[(size_t)nd * QLD + dim];
        float a = beta * (S + sb) + (1.f - beta) * outT + tbv;
        xn[(size_t)nd * 128 + dim] = fmaxf(a, 0.f);
    }
}

// ---------------- batchnorm ----------------
__global__ void bn_stats_k(const float* __restrict__ x, int N, float* __restrict__ stats) {
    int c = threadIdx.x;  // 128
    float s = 0.f, ss = 0.f;
    for (int n = blockIdx.x; n < N; n += gridDim.x) {
        float v = x[(size_t)n * 128 + c];
        s += v; ss += v * v;
    }
    atomicAdd(&stats[c], s);
    atomicAdd(&stats[128 + c], ss);
}

// bn apply + emit bf16 hi/lo split for the next GEMM (fused xsplit).
// The fp32 x buffer is DEAD after this (next layer reads only Xhi/Xlo) -> no store.
__global__ void bn_apply_k(const float* __restrict__ x, int N, const float* __restrict__ stats,
                           const float* __restrict__ g, const float* __restrict__ b,
                           unsigned short* __restrict__ Xhi, unsigned short* __restrict__ Xlo) {
    int idx = blockIdx.x * blockDim.x + threadIdx.x;
    if (idx >= N * 128) return;
    int c = idx & 127;
    float m = stats[c] / (float)N;
    float var = fmaxf(stats[128 + c] / (float)N - m * m, 0.f);
    float inv = rsqrtf(var + 1e-5f);
    float v = g[c] * (x[idx] - m) * inv + b[c];
    unsigned short h = f2bf(v);
    Xhi[idx] = h;
    Xlo[idx] = f2bf(v - bf2f(h));
}

// bn apply + pooling score in one pass (wave = node). grid N/4, block 256.
__global__ void bn_apply_score_k(float* __restrict__ x, int N, const float* __restrict__ stats,
                                 const float* __restrict__ g, const float* __restrict__ b,
                                 const float* __restrict__ w, float* __restrict__ s) {
    int node = blockIdx.x * 4 + (threadIdx.x >> 6);
    int lane = threadIdx.x & 63;
    int c0 = lane, c1 = lane + 64;
    float m0 = stats[c0] / (float)N;
    float v0 = fmaxf(stats[128 + c0] / (float)N - m0 * m0, 0.f);
    float m1 = stats[c1] / (float)N;
    float v1 = fmaxf(stats[128 + c1] / (float)N - m1 * m1, 0.f);
    float* row = x + (size_t)node * 128;
    float x0 = g[c0] * (row[c0] - m0) * rsqrtf(v0 + 1e-5f) + b[c0];
    float x1 = g[c1] * (row[c1] - m1) * rsqrtf(v1 + 1e-5f) + b[c1];
    row[c0] = x0;
    row[c1] = x1;
    float w0 = w[c0], w1 = w[c1];
    float p  = x0 * w0 + x1 * w1;
    float nw = w0 * w0 + w1 * w1;
#pragma unroll
    for (int off = 32; off; off >>= 1) {
        p  += __shfl_xor(p, off, 64);
        nw += __shfl_xor(nw, off, 64);
    }
    if (lane == 0) s[node] = p / sqrtf(nw);
}

// ---------------- pool0: topk + readout + CSR rebuild + bf16 split ----------------
// (xp fp32 gathered copy was dead — layer-2 consumes only Xhi/Xlo — removed.)
__global__ __launch_bounds__(128) void topk_pool0_k(
        const float* __restrict__ sc, const float* __restrict__ x,
        const int* __restrict__ src, const int* __restrict__ dst,
        float* __restrict__ rep,
        int* __restrict__ row_start, int* __restrict__ row_end,
        int* __restrict__ colb, int* __restrict__ eidb,
        unsigned short* __restrict__ Xhi, unsigned short* __restrict__ Xlo) {
    __shared__ float ls[128], th[64];
    __shared__ int lk[128], rk[128], oon[64];
    __shared__ int cnt[64], pref[64], cur[64];
    int g = blockIdx.x, t = threadIdx.x;
    float val = sc[g * 128 + t];
    ls[t] = val;
    __syncthreads();
    int c = 0;
    for (int j = 0; j < 128; ++j) {
        float vj = ls[j];
        c += (vj > val || (vj == val && j < t)) ? 1 : 0;
    }
    int kp = (c < 64) ? 1 : 0;
    lk[t] = kp;
    __syncthreads();
    int r = 0;
    for (int j = 0; j < t; ++j) r += lk[j];
    rk[t] = r;
    if (kp) { oon[r] = t; th[r] = tanhf(val); }
    __syncthreads();
    float mx = -INFINITY, sm = 0.f;
    for (int rr = 0; rr < 64; ++rr) {
        float v = x[(size_t)(g * 128 + oon[rr]) * 128 + t] * th[rr];
        int oidx = (g * 64 + rr) * 128 + t;
        unsigned short h = f2bf(v);
        Xhi[oidx] = h;
        Xlo[oidx] = f2bf(v - bf2f(h));
        mx = fmaxf(mx, v);
        sm += v;
    }
    rep[g * 256 + t] = mx;
    rep[g * 256 + 128 + t] = sm * (1.f / 64.f);
    if (t < 64) cnt[t] = 0;
    __syncthreads();
    int e0 = g * 512, nb = g * 128;
    int keepE[4], dr[4], sr[4];
#pragma unroll
    for (int i = 0; i < 4; ++i) {
        int e = e0 + t + i * 128;
        int s_ = src[e] - nb, d_ = dst[e] - nb;
        int ke = lk[s_] && lk[d_];
        keepE[i] = ke;
        dr[i] = rk[d_];
        sr[i] = rk[s_];
        if (ke) atomicAdd(&cnt[dr[i]], 1);
    }
    __syncthreads();
    if (t < 64) pref[t] = cnt[t];
    __syncthreads();
    for (int st = 1; st < 64; st <<= 1) {
        int v = (t < 64 && t >= st) ? pref[t - st] : 0;
        __syncthreads();
        if (t < 64) pref[t] += v;
        __syncthreads();
    }
    if (t < 64) {
        int ex = pref[t] - cnt[t];
        row_start[g * 64 + t] = e0 + ex;
        row_end[g * 64 + t]   = e0 + pref[t];
        cur[t] = ex;
    }
    __syncthreads();
#pragma unroll
    for (int i = 0; i < 4; ++i) {
        if (keepE[i]) {
            int pos = atomicAdd(&cur[dr[i]], 1);
            colb[e0 + pos] = g * 64 + sr[i];
            eidb[e0 + pos] = e0 + t + i * 128;
        }
    }
}

// ---------------- pool1: topk + readout only. n=64 -> k=32. block 128. ----------------------
__global__ __launch_bounds__(128) void topk_pool1_k(
        const float* __restrict__ sc, const float* __restrict__ x,
        float* __restrict__ rep) {
    __shared__ float ls[64], th[32];
    __shared__ int lk[64], oon[32];
    int g = blockIdx.x, t = threadIdx.x;
    float val = 0.f;
    if (t < 64) { val = sc[g * 64 + t]; ls[t] = val; }
    __syncthreads();
    if (t < 64) {
        int c = 0;
        for (int j = 0; j < 64; ++j) {
            float vj = ls[j];
            c += (vj > val || (vj == val && j < t)) ? 1 : 0;
        }
        int kp = (c < 32) ? 1 : 0;
        lk[t] = kp;
    }
    __syncthreads();
    if (t < 64 && lk[t]) {
        int r = 0;
        for (int j = 0; j < t; ++j) r += lk[j];
        oon[r] = t;
        th[r] = tanhf(val);
    }
    __syncthreads();
    float mx = -INFINITY, sm = 0.f;
    for (int rr = 0; rr < 32; ++rr) {
        float v = x[(size_t)(g * 64 + oon[rr]) * 128 + t] * th[rr];
        mx = fmaxf(mx, v);
        sm += v;
    }
    rep[g * 256 + t] = mx;
    rep[g * 256 + 128 + t] = sm * (1.f / 32.f);
}

// ---------------- MLP head: one block per graph, fp32 output ----------------
__global__ void head_k(const float* __restrict__ rep0, const float* __restrict__ rep1,
                       const float* __restrict__ W1, const float* __restrict__ b1,
                       const float* __restrict__ W2, const float* __restrict__ b2,
                       const float* __restrict__ W3, const float* __restrict__ b3,
                       float* __restrict__ out) {
    __shared__ float h[256], a1[256], a2[128], red[256];
    int g = blockIdx.x, t = threadIdx.x;  // 256
    h[t] = rep0[g * 256 + t] + rep1[g * 256 + t];
    __syncthreads();
    float acc = b1[t];
    for (int i = 0; i < 256; ++i) acc = fmaf(h[i], W1[i * 256 + t], acc);
    a1[t] = fmaxf(acc, 0.f);
    __syncthreads();
    if (t < 128) {
        float a = b2[t];
        for (int i = 0; i < 256; ++i) a = fmaf(a1[i], W2[i * 128 + t], a);
        a2[t] = fmaxf(a, 0.f);
    }
    __syncthreads();
    red[t] = (t < 128) ? a2[t] * W3[t] : 0.f;
    __syncthreads();
    for (int st = 128; st; st >>= 1) {
        if (t < st) red[t] += red[t + st];
        __syncthreads();
    }
    if (t == 0) out[g] = red[0] + b3[0];
}

// ======================================================================================
extern "C" void kernel_launch(void* const* d_in, const int* in_sizes, int n_in,
                              void* d_out, int out_size, void* d_ws, size_t ws_size,
                              hipStream_t stream) {
    (void)in_sizes; (void)n_in; (void)out_size; (void)ws_size;

    const float* x0    = (const float*)d_in[0];
    const int*   ei    = (const int*)d_in[1];
    const float* ea    = (const float*)d_in[2];
    const float* c1_Wq = (const float*)d_in[3];
    const float* c1_bq = (const float*)d_in[4];
    const float* c1_Wk = (const float*)d_in[5];
    const float* c1_bk = (const float*)d_in[6];
    const float* c1_Wv = (const float*)d_in[7];
    const float* c1_bv = (const float*)d_in[8];
    const float* c1_We = (const float*)d_in[9];
    const float* c1_Ws = (const float*)d_in[10];
    const float* c1_bs = (const float*)d_in[11];
    const float* c1_Wb = (const float*)d_in[12];
    const float* t1_W  = (const float*)d_in[13];
    const float* t1_b  = (const float*)d_in[14];
    const float* bn1_g = (const float*)d_in[15];
    const float* bn1_b = (const float*)d_in[16];
    const float* cl_Wq = (const float*)d_in[17];
    const float* cl_bq = (const float*)d_in[18];
    const float* cl_Wk = (const float*)d_in[19];
    const float* cl_bk = (const float*)d_in[20];
    const float* cl_Wv = (const float*)d_in[21];
    const float* cl_bv = (const float*)d_in[22];
    const float* cl_We = (const float*)d_in[23];
    const float* cl_Ws = (const float*)d_in[24];
    const float* cl_bs = (const float*)d_in[25];
    const float* cl_Wb = (const float*)d_in[26];
    const float* tl_W  = (const float*)d_in[27];
    const float* tl_b  = (const float*)d_in[28];
    const float* bnl_g = (const float*)d_in[29];
    const float* bnl_b = (const float*)d_in[30];
    const float* pool_w= (const float*)d_in[31];
    const float* l1_W  = (const float*)d_in[32];
    const float* l1_b  = (const float*)d_in[33];
    const float* l2_W  = (const float*)d_in[34];
    const float* l2_b  = (const float*)d_in[35];
    const float* l3_W  = (const float*)d_in[36];
    const float* l3_b  = (const float*)d_in[37];
    float* out = (float*)d_out;

    // -------- workspace layout (~138 MB) --------
    char* base = (char*)d_ws;
    size_t off = 0;
    auto alloc = [&](size_t bytes) -> void* {
        void* p = base + off;
        off += (bytes + 255) & ~(size_t)255;
        return p;
    };
    float* QB   = (float*)alloc((size_t)16384 * QLD * 4);   // 109 MB
    float* xA   = (float*)alloc((size_t)16384 * 128 * 4);
    float* xB   = (float*)alloc((size_t)16384 * 128 * 4);
    float* UB   = (float*)alloc((size_t)16384 * 64 * 4);
    float* VZB  = (float*)alloc((size_t)16384 * 4 * 4);
    float* SZB  = (float*)alloc((size_t)16384 * 4);
    float* stats  = (float*)alloc(256 * 4);
    float* scores = (float*)alloc(16384 * 4);
    float* rep0   = (float*)alloc(128 * 256 * 4);
    float* rep1   = (float*)alloc(128 * 256 * 4);
    int* row_start = (int*)alloc(16384 * 4);
    int* row_end   = (int*)alloc(16384 * 4);
    int* colb      = (int*)alloc(E_TOT * 4);
    int* eidb      = (int*)alloc(E_TOT * 4);
    unsigned short* Xhi = (unsigned short*)alloc((size_t)16384 * 128 * 2);  // 4.2 MB
    unsigned short* Xlo = (unsigned short*)alloc((size_t)16384 * 128 * 2);  // 4.2 MB

    // per-layer prep buffers
    LayerPrep P[3];
    const float* Wb_[3] = {c1_Wb, cl_Wb, cl_Wb + 1536};
    const float* Wk_[3] = {c1_Wk, cl_Wk, cl_Wk + 65536};
    for (int l = 0; l < 3; ++l) {
        LayerPrep& p = P[l];
        p.Wst  = (float*)alloc(128 * 128 * 4);
        p.ws_z = (float*)alloc(128 * 4);
        p.sbt  = (float*)alloc(128 * 4);
        p.zb   = (float*)alloc(16);
        p.Wu   = (float*)alloc(128 * 64 * 4);
        p.bu   = (float*)alloc(64 * 4);
        p.Wet  = (float*)alloc(64 * 128 * 4);
        p.wez  = (float*)alloc(64 * 4);
        p.Wvt  = (float*)alloc(128 * 512 * 4);
        p.bvt  = (float*)alloc(512 * 4);
        p.Wvz  = (float*)alloc(128 * 4 * 4);
        p.bvz  = (float*)alloc(16);
        p.Whi  = (unsigned short*)alloc((size_t)NCOL * 128 * 2);
        p.Wlo  = (unsigned short*)alloc((size_t)NCOL * 128 * 2);
    }
    P[0].Ws = c1_Ws; P[0].bs_ = c1_bs; P[0].Wq = c1_Wq; P[0].bq = c1_bq;
    P[0].We = c1_We; P[0].Wv = c1_Wv; P[0].bv = c1_bv; P[0].tW = t1_W; P[0].Fin = 64;
    P[1].Ws = cl_Ws; P[1].bs_ = cl_bs; P[1].Wq = cl_Wq; P[1].bq = cl_bq;
    P[1].We = cl_We; P[1].Wv = cl_Wv; P[1].bv = cl_bv; P[1].tW = tl_W; P[1].Fin = 128;
    P[2].Ws = cl_Ws + 65536; P[2].bs_ = cl_bs + 512; P[2].Wq = cl_Wq + 65536;
    P[2].bq = cl_bq + 512; P[2].We = cl_We + 8192; P[2].Wv = cl_Wv + 65536;
    P[2].bv = cl_bv + 512; P[2].tW = tl_W + 65536; P[2].Fin = 128;

    // ---- all weight prep up front, 3 layers wide (activation-independent) ----
    {
        int unitsMax = (10 * 128 + 138) + (69 * 128 + 133);
        prep_all_k<<<dim3((unitsMax + 3) / 4, 3), 256, 0, stream>>>(P[0], P[1], P[2],
                                                                    Wb_[0], Wb_[1], Wb_[2]);
        wsplit_all_k<<<dim3((NCOL * 128 + 255) / 256, 3), 256, 0, stream>>>(P[0], P[1], P[2],
                                                                            Wk_[0], Wk_[1], Wk_[2]);
    }

    // ---- CSR over original edges + input split ----
    csr_graph_k<<<B_G, 128, 0, stream>>>(ei, ei + E_TOT, row_start, row_end, colb, eidb);
    xsplit_k<<<(16384 * 64 / 4 + 255) / 256, 256, 0, stream>>>(x0, 16384 * 64 / 4, Xhi, Xlo);

    auto tconv = [&](int L, int N, const float* bq, const float* bk, const float* tb,
                     float* xn) {
        int nwg8 = 28 * (N / 128) / 8;
        if (P[L].Fin == 64)
            qkvs_mfma<64><<<dim3(28, N / 128), 256, 0, stream>>>(Xhi, Xlo, P[L].Whi, P[L].Wlo,
                                                                 bq, bk, P[L].bvt, P[L].bu,
                                                                 P[L].bvz, P[L].zb,
                                                                 QB, UB, VZB, SZB, nwg8);
        else
            qkvs_mfma<128><<<dim3(28, N / 128), 256, 0, stream>>>(Xhi, Xlo, P[L].Whi, P[L].Wlo,
                                                                  bq, bk, P[L].bvt, P[L].bu,
                                                                  P[L].bvz, P[L].zb,
                                                                  QB, UB, VZB, SZB, nwg8);
        attn_combine_k<<<N / 4, 256, 0, stream>>>(QB, UB, VZB, SZB,
                                                  row_start, row_end, colb, eidb,
                                                  ea, P[L].wez, P[L].Wet, P[L].sbt, tb,
                                                  xn, N / 32, stats);
    };

    // ---- layer 1: tconv(Fin=64) + t1 + bn1 ----
    tconv(0, 16384, c1_bq, c1_bk, t1_b, xA);
    bn_stats_k<<<512, 128, 0, stream>>>(xA, 16384, stats);
    bn_apply_k<<<(16384 * 128 + 255) / 256, 256, 0, stream>>>(xA, 16384, stats, bn1_g, bn1_b,
                                                              Xhi, Xlo);

    // ---- loop layer 0 (Fin=128, N=16384) ----
    tconv(1, 16384, cl_bq, cl_bk, tl_b, xB);
    bn_stats_k<<<512, 128, 0, stream>>>(xB, 16384, stats);
    bn_apply_score_k<<<16384 / 4, 256, 0, stream>>>(xB, 16384, stats, bnl_g, bnl_b,
                                                    pool_w, scores);

    // ---- pool 0 (fused topk+readout+CSR+split) ----
    topk_pool0_k<<<B_G, 128, 0, stream>>>(scores, xB, ei, ei + E_TOT, rep0,
                                          row_start, row_end, colb, eidb, Xhi, Xlo);

    // ---- loop layer 1 (Fin=128, N=8192) ----
    tconv(2, 8192, cl_bq + 512, cl_bk + 512, tl_b + 128, xB);
    bn_stats_k<<<512, 128, 0, stream>>>(xB, 8192, stats);
    bn_apply_score_k<<<8192 / 4, 256, 0, stream>>>(xB, 8192, stats, bnl_g + 128, bnl_b + 128,
                                                   pool_w + 128, scores);

    // ---- pool 1 (fused topk+readout) ----
    topk_pool1_k<<<B_G, 128, 0, stream>>>(scores, xB, rep1);

    // ---- MLP head (fp32 out) ----
    head_k<<<B_G, 256, 0, stream>>>(rep0, rep1, l1_W, l1_b, l2_W, l2_b, l3_W, l3_b, out);
}

// Round 12
// 458.663 us; speedup vs baseline: 1.3101x; 1.0467x over previous
//
#include <hip/hip_runtime.h>
#include <math.h>

#define E_TOT 65536
#define B_G   128
#define QLD   1664   // fused buffer row: [S(128) | Q(512) | K(512) | VT(512)]
#define NCOL  1792   // GEMM cols: S|Q|K|VT (1664) + U(64) + VZ(4) + SZ(1) + pad(59, masked)

typedef __attribute__((ext_vector_type(8))) short short8;
typedef __attribute__((ext_vector_type(4))) short short4v;
typedef __attribute__((ext_vector_type(4))) float float4v;

__device__ __forceinline__ unsigned short f2bf(float f) {
    unsigned int u = __float_as_uint(f);
    unsigned int r = u + 0x7FFFu + ((u >> 16) & 1u);   // round-to-nearest-even
    return (unsigned short)(r >> 16);
}
__device__ __forceinline__ float bf2f(unsigned short h) {
    return __uint_as_float(((unsigned int)h) << 16);
}

// per-layer weight-prep pointer bundle (passed by value; uniform selects -> SGPRs)
struct LayerPrep {
    const float *Ws, *bs_, *Wq, *bq, *We, *Wv, *bv, *tW;
    float *Wst, *ws_z, *sbt, *zb, *Wu, *bu, *Wet, *wez, *Wvt, *bvt, *Wvz, *bvz;
    unsigned short *Whi, *Wlo;
    int Fin;
};

__device__ __forceinline__ LayerPrep pick(const LayerPrep& p0, const LayerPrep& p1,
                                          const LayerPrep& p2) {
    return blockIdx.y == 0 ? p0 : (blockIdx.y == 1 ? p1 : p2);
}

// ---------------- per-layer weight prep, lane-per-output (round-5 version, measured fast)
__global__ void prep_all_k(LayerPrep p0, LayerPrep p1, LayerPrep p2, const float* Wb0,
                           const float* Wb1, const float* Wb2) {
    LayerPrep p = pick(p0, p1, p2);
    const float* Wb = blockIdx.y == 0 ? Wb0 : (blockIdx.y == 1 ? Wb1 : Wb2);
    int Fin = p.Fin;
    int w = blockIdx.x * 4 + (threadIdx.x >> 6);
    int lane = threadIdx.x & 63;

    // ---- P1 unit map ----
    int U1 = Fin * 2;          // Wst
    int U2 = U1 + 2;           // sbt
    int U3 = U2 + Fin * 8;     // Wvt
    int U4 = U3 + 8;           // bvt
    int U5 = U4 + 128;         // Wet
    if (w < U5) {
        const float* A; const float* bp; float* outp; int R;
        if (w < U1) {
            int f = w >> 1, m0 = (w & 1) * 64;
            A = p.Ws + (size_t)f * 512; bp = p.tW + m0 + lane;
            outp = p.Wst + f * 128 + m0 + lane; R = 512;
        } else if (w < U2) {
            int m0 = (w - U1) * 64;
            A = p.bs_; bp = p.tW + m0 + lane;
            outp = p.sbt + m0 + lane; R = 512;
        } else if (w < U3) {
            int u = w - U2; int f = u >> 3, q = u & 7;
            int cb = (q >> 1) * 128, m0 = (q & 1) * 64;
            A = p.Wv + (size_t)f * 512 + cb; bp = p.tW + cb * 128 + m0 + lane;
            outp = p.Wvt + (size_t)f * 512 + q * 64 + lane; R = 128;
        } else if (w < U4) {
            int q = w - U3; int cb = (q >> 1) * 128, m0 = (q & 1) * 64;
            A = p.bv + cb; bp = p.tW + cb * 128 + m0 + lane;
            outp = p.bvt + q * 64 + lane; R = 128;
        } else {
            int u = w - U4; int j2 = u >> 1, m0 = (u & 1) * 64;
            int j = j2 & 15, cb = (j2 >> 4) * 128;
            A = p.We + j * 512 + cb; bp = p.tW + cb * 128 + m0 + lane;
            outp = p.Wet + j2 * 128 + m0 + lane; R = 128;
        }
        float a0 = 0.f, a1 = 0.f, a2 = 0.f, a3 = 0.f;
        for (int c = 0; c < R; c += 4) {
            a0 = fmaf(A[c],     bp[0],   a0);
            a1 = fmaf(A[c + 1], bp[128], a1);
            a2 = fmaf(A[c + 2], bp[256], a2);
            a3 = fmaf(A[c + 3], bp[384], a3);
            bp += 512;
        }
        *outp = (a0 + a1) + (a2 + a3);
        return;
    }

    // ---- P2 units ----
    int w2 = w - U5;
    int q1 = Fin, q2 = q1 + 1, q3 = q2 + Fin * 64, q4 = q3 + 64, q5 = q4 + 64;
    int q6 = q5 + Fin * 4, q7 = q6 + 4;
    if (w2 >= q7) return;
    float s = 0.f;
    if (w2 < q1) {
        int f = w2;
        for (int c = lane; c < 512; c += 64)
            s = fmaf(p.Ws[(size_t)f * 512 + c], Wb[512 + c] - Wb[1024 + c], s);
    } else if (w2 < q2) {
        for (int c = lane; c < 512; c += 64)
            s = fmaf(p.bs_[c], Wb[512 + c] - Wb[1024 + c], s);
    } else if (w2 < q3) {   // Wu
        int q = w2 - q2; int f = q >> 6; int j2 = q & 63;
        int j = j2 & 15; int cb = (j2 >> 4) * 128;
        s = p.Wq[(size_t)f * 512 + cb + lane] * p.We[j * 512 + cb + lane]
          + p.Wq[(size_t)f * 512 + cb + lane + 64] * p.We[j * 512 + cb + lane + 64];
    } else if (w2 < q4) {   // bu
        int j2 = w2 - q3; int j = j2 & 15; int cb = (j2 >> 4) * 128;
        s = p.bq[cb + lane] * p.We[j * 512 + cb + lane]
          + p.bq[cb + lane + 64] * p.We[j * 512 + cb + lane + 64];
    } else if (w2 < q5) {   // wez
        int j2 = w2 - q4; int j = j2 & 15; int cb = (j2 >> 4) * 128;
        s = p.We[j * 512 + cb + lane] * (Wb[cb + lane] + Wb[1024 + cb + lane])
          + p.We[j * 512 + cb + lane + 64] * (Wb[cb + lane + 64] + Wb[1024 + cb + lane + 64]);
    } else if (w2 < q6) {   // Wvz
        int q = w2 - q5; int f = q >> 2; int cb = (q & 3) * 128;
        s = p.Wv[(size_t)f * 512 + cb + lane] * (Wb[cb + lane] + Wb[1024 + cb + lane])
          + p.Wv[(size_t)f * 512 + cb + lane + 64] * (Wb[cb + lane + 64] + Wb[1024 + cb + lane + 64]);
    } else {                // bvz
        int cb = (w2 - q6) * 128;
        s = p.bv[cb + lane] * (Wb[cb + lane] + Wb[1024 + cb + lane])
          + p.bv[cb + lane + 64] * (Wb[cb + lane + 64] + Wb[1024 + cb + lane + 64]);
    }
#pragma unroll
    for (int off = 32; off; off >>= 1) s += __shfl_xor(s, off, 64);
    if (lane == 0) {
        if (w2 < q1) p.ws_z[w2] = s;
        else if (w2 < q2) p.zb[0] = s;
        else if (w2 < q3) p.Wu[w2 - q2] = s;
        else if (w2 < q4) p.bu[w2 - q3] = s;
        else if (w2 < q5) p.wez[w2 - q4] = s;
        else if (w2 < q6) p.Wvz[w2 - q5] = s;
        else p.bvz[w2 - q6] = s;
    }
}

// Wt[col][k] transposed+split from [Wst | Wq | Wk | Wvt | Wu | Wvz | ws_z | pad], 3 layers wide
__global__ void wsplit_all_k(LayerPrep p0, LayerPrep p1, LayerPrep p2,
                             const float* Wk0, const float* Wk1, const float* Wk2) {
    LayerPrep p = pick(p0, p1, p2);
    const float* Wk = blockIdx.y == 0 ? Wk0 : (blockIdx.y == 1 ? Wk1 : Wk2);
    int K = p.Fin, kshift = (K == 64) ? 6 : 7;
    int idx = blockIdx.x * 256 + threadIdx.x;
    if (idx >= NCOL * K) return;
    int col = idx >> kshift, k = idx & (K - 1);
    float w;
    if (col < 128)       w = p.Wst[k * 128 + col];
    else if (col < 640)  w = p.Wq[(size_t)k * 512 + col - 128];
    else if (col < 1152) w = Wk[(size_t)k * 512 + col - 640];
    else if (col < 1664) w = p.Wvt[(size_t)k * 512 + col - 1152];
    else if (col < 1728) w = p.Wu[(size_t)k * 64 + col - 1664];
    else if (col < 1732) w = p.Wvz[(size_t)k * 4 + col - 1728];
    else if (col == 1732) w = p.ws_z[k];
    else                 w = 0.f;
    unsigned short h = f2bf(w);
    p.Whi[idx] = h;
    p.Wlo[idx] = f2bf(w - bf2f(h));
}

// X split to bf16 hi/lo (only needed standalone for the fp32 network input x0)
__global__ void xsplit_k(const float* __restrict__ X, int total4,
                         unsigned short* __restrict__ Xhi, unsigned short* __restrict__ Xlo) {
    int idx = blockIdx.x * 256 + threadIdx.x;
    if (idx >= total4) return;
    float4 f = ((const float4*)X)[idx];
    unsigned short h0 = f2bf(f.x), h1 = f2bf(f.y), h2 = f2bf(f.z), h3 = f2bf(f.w);
    short4v hv = {(short)h0, (short)h1, (short)h2, (short)h3};
    short4v lv = {(short)f2bf(f.x - bf2f(h0)), (short)f2bf(f.y - bf2f(h1)),
                  (short)f2bf(f.z - bf2f(h2)), (short)f2bf(f.w - bf2f(h3))};
    *(short4v*)(Xhi + (size_t)idx * 4) = hv;
    *(short4v*)(Xlo + (size_t)idx * 4) = lv;
}

// ---------------- fused S/Q/K/VT/U/VZ/SZ GEMM via split-bf16 MFMA ----------------
// Round-7 structure (measured best): grid (28, N/128), 4 waves, 20 KB LDS, per-chunk
// LDS staging with next-chunk register prefetch (T14), LDS-transposed coalesced epilogue.
template <int KT>
__global__ __launch_bounds__(256) void qkvs_mfma(
        const unsigned short* __restrict__ Xhi, const unsigned short* __restrict__ Xlo,
        const unsigned short* __restrict__ Whi, const unsigned short* __restrict__ Wlo,
        const float* __restrict__ bq, const float* __restrict__ bk,
        const float* __restrict__ bvt, const float* __restrict__ bu,
        const float* __restrict__ bvz, const float* __restrict__ zb,
        float* __restrict__ out, float* __restrict__ UB, float* __restrict__ VZB,
        float* __restrict__ SZB, int nwg8) {
    constexpr int NKC = KT >> 5;            // 2 (K=64) or 4 (K=128)
    constexpr int NCH = KT >> 6;            // 1 or 2
    __shared__ __align__(16) unsigned short bs[2 * 64 * 80];   // 20 KB
    const int ldb = 80, loHalf = 64 * 80;
    int tid = threadIdx.x;
    int wave = tid >> 6, lane = tid & 63;
    int m = lane & 15, kg = lane >> 4;
    int hw = blockIdx.y * 28 + blockIdx.x;
    int lb = (hw & 7) * nwg8 + (hw >> 3);   // bijective (nwg % 8 == 0)
    int rowBase = (lb / 28) * 128;
    int n0 = rowBase + wave * 32;
    int c0 = (lb % 28) * 64;

    short8 ahi[2][NKC], alo[2][NKC];
#pragma unroll
    for (int rt = 0; rt < 2; ++rt) {
        const unsigned short* xh = Xhi + (size_t)(n0 + rt * 16 + m) * KT + kg * 8;
        const unsigned short* xl = Xlo + (size_t)(n0 + rt * 16 + m) * KT + kg * 8;
#pragma unroll
        for (int kc = 0; kc < NKC; ++kc) {
            ahi[rt][kc] = *(const short8*)(xh + kc * 32);
            alo[rt][kc] = *(const short8*)(xl + kc * 32);
        }
    }

    float4v acc[2][4];
#pragma unroll
    for (int rt = 0; rt < 2; ++rt)
#pragma unroll
        for (int ct = 0; ct < 4; ++ct) acc[rt][ct] = (float4v){0.f, 0.f, 0.f, 0.f};

    // stage registers: [buf][iter]  (2 iters of 256 threads cover 64 cols x 64 k)
    short8 ph[2][2], pl[2][2];
#pragma unroll
    for (int it = 0; it < 2; ++it) {
        int i = tid + it * 256; int col = i >> 3, part = i & 7;
        ph[0][it] = *(const short8*)(Whi + (size_t)(c0 + col) * KT + part * 8);
        pl[0][it] = *(const short8*)(Wlo + (size_t)(c0 + col) * KT + part * 8);
    }

#pragma unroll
    for (int ch = 0; ch < NCH; ++ch) {
        if (ch) __syncthreads();            // previous compute done reading bs
#pragma unroll
        for (int it = 0; it < 2; ++it) {
            int i = tid + it * 256; int col = i >> 3, part = i & 7;
            *(short8*)(bs + col * ldb + part * 8) = ph[ch & 1][it];
            *(short8*)(bs + loHalf + col * ldb + part * 8) = pl[ch & 1][it];
        }
        __syncthreads();
        if (ch + 1 < NCH) {                 // issue next chunk early (T14)
#pragma unroll
            for (int it = 0; it < 2; ++it) {
                int i = tid + it * 256; int col = i >> 3, part = i & 7;
                ph[(ch + 1) & 1][it] =
                    *(const short8*)(Whi + (size_t)(c0 + col) * KT + (ch + 1) * 64 + part * 8);
                pl[(ch + 1) & 1][it] =
                    *(const short8*)(Wlo + (size_t)(c0 + col) * KT + (ch + 1) * 64 + part * 8);
            }
        }
#pragma unroll
        for (int kc2 = 0; kc2 < 2; ++kc2) {
            const int kc = ch * 2 + kc2;    // compile-time constant after unroll
#pragma unroll
            for (int ct = 0; ct < 4; ++ct) {
                const unsigned short* bp = bs + (ct * 16 + m) * ldb + kg * 8 + kc2 * 32;
                short8 bhi = *(const short8*)(bp);
                short8 blo = *(const short8*)(bp + loHalf);
                acc[0][ct] = __builtin_amdgcn_mfma_f32_16x16x32_bf16(ahi[0][kc], bhi, acc[0][ct], 0, 0, 0);
                acc[0][ct] = __builtin_amdgcn_mfma_f32_16x16x32_bf16(alo[0][kc], bhi, acc[0][ct], 0, 0, 0);
                acc[0][ct] = __builtin_amdgcn_mfma_f32_16x16x32_bf16(ahi[0][kc], blo, acc[0][ct], 0, 0, 0);
                acc[1][ct] = __builtin_amdgcn_mfma_f32_16x16x32_bf16(ahi[1][kc], bhi, acc[1][ct], 0, 0, 0);
                acc[1][ct] = __builtin_amdgcn_mfma_f32_16x16x32_bf16(alo[1][kc], bhi, acc[1][ct], 0, 0, 0);
                acc[1][ct] = __builtin_amdgcn_mfma_f32_16x16x32_bf16(ahi[1][kc], blo, acc[1][ct], 0, 0, 0);
            }
        }
    }

    float bias[4];
#pragma unroll
    for (int ct = 0; ct < 4; ++ct) {
        int col = c0 + ct * 16 + m;
        float bv_;
        if (col < 128)       bv_ = 0.f;
        else if (col < 640)  bv_ = bq[col - 128];
        else if (col < 1152) bv_ = bk[col - 640];
        else if (col < 1664) bv_ = bvt[col - 1152];
        else if (col < 1728) bv_ = bu[col - 1664];
        else if (col < 1732) bv_ = bvz[col - 1728];
        else if (col == 1732) bv_ = zb[0];
        else                 bv_ = 0.f;
        bias[ct] = bv_;
    }

    if (c0 < 1664) {
        // ---- coalesced epilogue via LDS transpose (all 64 cols -> out) ----
        float* fs = (float*)bs;             // reuse; need 64*68*4 = 17408 B <= 20480
        const int lds_s = 68;               // 16B-aligned rows, 2-way bank aliasing (free)
#pragma unroll
        for (int rt = 0; rt < 2; ++rt) {
            __syncthreads();                // compute (rt=0) / prev read pass (rt=1) done
#pragma unroll
            for (int ct = 0; ct < 4; ++ct)
#pragma unroll
                for (int r = 0; r < 4; ++r) {
                    int row_l = wave * 16 + kg * 4 + r;     // 0..63
                    fs[row_l * lds_s + ct * 16 + m] = acc[rt][ct][r] + bias[ct];
                }
            __syncthreads();
            int ch4 = tid & 15;             // 16B chunk within the 256B row
            int rbase = tid >> 4;           // 0..15
#pragma unroll
            for (int it = 0; it < 4; ++it) {
                int rl = it * 16 + rbase;   // 0..63
                float4 v = *(const float4*)(fs + rl * lds_s + ch4 * 4);
                int row = rowBase + (rl >> 4) * 32 + rt * 16 + (rl & 15);
                *(float4*)(out + (size_t)row * QLD + c0 + ch4 * 4) = v;
            }
        }
    } else {
        // ---- scalar path for the U/VZ/SZ col-blocks (lb%28 == 26,27) ----
#pragma unroll
        for (int ct = 0; ct < 4; ++ct) {
            int col = c0 + ct * 16 + m;
            if (col > 1732) continue;
#pragma unroll
            for (int rt = 0; rt < 2; ++rt) {
#pragma unroll
                for (int r = 0; r < 4; ++r) {
                    int row = n0 + rt * 16 + kg * 4 + r;
                    float v = acc[rt][ct][r] + bias[ct];
                    if (col < 1728)      UB[(size_t)row * 64 + col - 1664] = v;
                    else if (col < 1732) VZB[(size_t)row * 4 + col - 1728] = v;
                    else                 SZB[row] = v;
                }
            }
        }
    }
}

// ---------------- per-graph CSR build (edges of graph g are [g*512,(g+1)*512)) --------------
__global__ __launch_bounds__(128) void csr_graph_k(const int* __restrict__ src,
                                                   const int* __restrict__ dst,
                                                   int* __restrict__ row_start,
                                                   int* __restrict__ row_end,
                                                   int* __restrict__ colb,
                                                   int* __restrict__ eidb) {
    __shared__ int cnt[128], pref[128], cur[128];
    int g = blockIdx.x, t = threadIdx.x;
    cnt[t] = 0;
    __syncthreads();
    int e0 = g * 512, nb = g * 128;
    int dl[4], sl[4];
#pragma unroll
    for (int i = 0; i < 4; ++i) {
        int e = e0 + t + i * 128;
        dl[i] = dst[e] - nb;
        sl[i] = src[e];
        atomicAdd(&cnt[dl[i]], 1);
    }
    __syncthreads();
    pref[t] = cnt[t];
    __syncthreads();
    for (int st = 1; st < 128; st <<= 1) {
        int v = (t >= st) ? pref[t - st] : 0;
        __syncthreads();
        pref[t] += v;
        __syncthreads();
    }
    int ex = pref[t] - cnt[t];
    row_start[nb + t] = e0 + ex;
    row_end[nb + t]   = e0 + pref[t];
    cur[t] = ex;
    __syncthreads();
#pragma unroll
    for (int i = 0; i < 4; ++i) {
        int pos = atomicAdd(&cur[dl[i]], 1);
        colb[e0 + pos] = sl[i];
        eidb[e0 + pos] = e0 + t + i * 128;
    }
}

// ---------------- attention + combine + t-layer epilogue, fully fused ----------------
// Node-per-group layout (avg in-degree 4): wave = head, 16-lane group owns one node.
// ONE barrier per block; epilogue for 4 nodes on all 256 threads. XCD-swizzled block id.
// Block 0 zeroes the bn `stats` buffer (consumed by the following bn_stats_k pass).
__global__ __launch_bounds__(256) void attn_combine_k(
        const float* __restrict__ QB, const float* __restrict__ UB,
        const float* __restrict__ VZB, const float* __restrict__ SZB,
        const int* __restrict__ row_start, const int* __restrict__ row_end,
        const int* __restrict__ colb, const int* __restrict__ eidb,
        const float* __restrict__ ea, const float* __restrict__ wez,
        const float* __restrict__ Wet, const float* __restrict__ sbt,
        const float* __restrict__ tb, float* __restrict__ xn, int nwg8,
        float* __restrict__ statsZ) {
    __shared__ float shO[4][4][128];   // [nodeSlot][head][dim]  8 KB
    __shared__ float tsh[4][64];       // [nodeSlot][head*16+li] 1 KB
    __shared__ float zsh[4][4];
    int tid = threadIdx.x;
    int head = tid >> 6, lane = tid & 63;
    int grp = lane >> 4, li = lane & 15;
    int bid = blockIdx.x;
    if (bid == 0) statsZ[tid] = 0.f;          // 256 floats; consumed by bn_stats later
    int lb = (bid & 7) * nwg8 + (bid >> 3);   // bijective (grid % 8 == 0)
    int node = lb * 4 + grp;

    float wezv = wez[head * 16 + li];
    const float* Qr = QB + (size_t)node * QLD + 128 + head * 128 + li * 8;
    float4 q0 = *(const float4*)Qr;
    float4 q1 = *(const float4*)(Qr + 4);
    float uu = UB[(size_t)node * 64 + head * 16 + li];
    int beg = row_start[node], end = row_end[node];

    float l = 0.f, t = 0.f, zac = 0.f;
    float4 a0 = {0.f, 0.f, 0.f, 0.f}, a1 = {0.f, 0.f, 0.f, 0.f};
    const float scale = 0.08838834764831845f;  // 1/sqrt(128); alpha O(10), exp safe
    int j = beg;
    for (; j + 1 < end; j += 2) {              // 2 independent gathers in flight
        int s1 = colb[j],     e1 = eidb[j];
        int s2 = colb[j + 1], e2 = eidb[j + 1];
        const float* K1 = QB + (size_t)s1 * QLD + 640 + head * 128 + li * 8;
        const float* V1 = QB + (size_t)s1 * QLD + 1152 + head * 128 + li * 8;
        const float* K2 = QB + (size_t)s2 * QLD + 640 + head * 128 + li * 8;
        const float* V2 = QB + (size_t)s2 * QLD + 1152 + head * 128 + li * 8;
        float4 k10 = *(const float4*)K1, k11 = *(const float4*)(K1 + 4);
        float4 v10 = *(const float4*)V1, v11 = *(const float4*)(V1 + 4);
        float4 k20 = *(const float4*)K2, k21 = *(const float4*)(K2 + 4);
        float4 v20 = *(const float4*)V2, v21 = *(const float4*)(V2 + 4);
        float ea1 = ea[(size_t)e1 * 16 + li];
        float ea2 = ea[(size_t)e2 * 16 + li];
        float vz1 = VZB[(size_t)s1 * 4 + head];
        float vz2 = VZB[(size_t)s2 * 4 + head];
        float p1 = q0.x * k10.x + q0.y * k10.y + q0.z * k10.z + q0.w * k10.w
                 + q1.x * k11.x + q1.y * k11.y + q1.z * k11.z + q1.w * k11.w + ea1 * uu;
        float p2 = q0.x * k20.x + q0.y * k20.y + q0.z * k20.z + q0.w * k20.w
                 + q1.x * k21.x + q1.y * k21.y + q1.z * k21.z + q1.w * k21.w + ea2 * uu;
        p1 += __shfl_xor(p1, 1, 64); p1 += __shfl_xor(p1, 2, 64);
        p1 += __shfl_xor(p1, 4, 64); p1 += __shfl_xor(p1, 8, 64);
        p2 += __shfl_xor(p2, 1, 64); p2 += __shfl_xor(p2, 2, 64);
        p2 += __shfl_xor(p2, 4, 64); p2 += __shfl_xor(p2, 8, 64);
        float w1 = expf(p1 * scale), w2 = expf(p2 * scale);
        l += w1; l += w2;
        t = fmaf(w1, ea1, t); t = fmaf(w2, ea2, t);
        zac = fmaf(w1, vz1, zac); zac = fmaf(w2, vz2, zac);
        a0.x = fmaf(w1, v10.x, a0.x); a0.y = fmaf(w1, v10.y, a0.y);
        a0.z = fmaf(w1, v10.z, a0.z); a0.w = fmaf(w1, v10.w, a0.w);
        a1.x = fmaf(w1, v11.x, a1.x); a1.y = fmaf(w1, v11.y, a1.y);
        a1.z = fmaf(w1, v11.z, a1.z); a1.w = fmaf(w1, v11.w, a1.w);
        a0.x = fmaf(w2, v20.x, a0.x); a0.y = fmaf(w2, v20.y, a0.y);
        a0.z = fmaf(w2, v20.z, a0.z); a0.w = fmaf(w2, v20.w, a0.w);
        a1.x = fmaf(w2, v21.x, a1.x); a1.y = fmaf(w2, v21.y, a1.y);
        a1.z = fmaf(w2, v21.z, a1.z); a1.w = fmaf(w2, v21.w, a1.w);
    }
    if (j < end) {                              // tail edge
        int s1 = colb[j], e1 = eidb[j];
        const float* K1 = QB + (size_t)s1 * QLD + 640 + head * 128 + li * 8;
        const float* V1 = QB + (size_t)s1 * QLD + 1152 + head * 128 + li * 8;
        float4 k10 = *(const float4*)K1, k11 = *(const float4*)(K1 + 4);
        float4 v10 = *(const float4*)V1, v11 = *(const float4*)(V1 + 4);
        float ea1 = ea[(size_t)e1 * 16 + li];
        float vz1 = VZB[(size_t)s1 * 4 + head];
        float p1 = q0.x * k10.x + q0.y * k10.y + q0.z * k10.z + q0.w * k10.w
                 + q1.x * k11.x + q1.y * k11.y + q1.z * k11.z + q1.w * k11.w + ea1 * uu;
        p1 += __shfl_xor(p1, 1, 64); p1 += __shfl_xor(p1, 2, 64);
        p1 += __shfl_xor(p1, 4, 64); p1 += __shfl_xor(p1, 8, 64);
        float w1 = expf(p1 * scale);
        l += w1;
        t = fmaf(w1, ea1, t);
        zac = fmaf(w1, vz1, zac);
        a0.x = fmaf(w1, v10.x, a0.x); a0.y = fmaf(w1, v10.y, a0.y);
        a0.z = fmaf(w1, v10.z, a0.z); a0.w = fmaf(w1, v10.w, a0.w);
        a1.x = fmaf(w1, v11.x, a1.x); a1.y = fmaf(w1, v11.y, a1.y);
        a1.z = fmaf(w1, v11.z, a1.z); a1.w = fmaf(w1, v11.w, a1.w);
    }

    float inv = 1.f / (l + 1e-16f);
    float tn = t * inv;
    float zw = tn * wezv;
    zw += __shfl_xor(zw, 1, 64); zw += __shfl_xor(zw, 2, 64);
    zw += __shfl_xor(zw, 4, 64); zw += __shfl_xor(zw, 8, 64);
    float z = zac * inv + zw;

    float* op = &shO[grp][head][li * 8];
    op[0] = a0.x * inv; op[1] = a0.y * inv; op[2] = a0.z * inv; op[3] = a0.w * inv;
    op[4] = a1.x * inv; op[5] = a1.y * inv; op[6] = a1.z * inv; op[7] = a1.w * inv;
    tsh[grp][head * 16 + li] = tn;
    if (li == 0) zsh[grp][head] = z;
    __syncthreads();

    // epilogue: 512 outputs (4 nodes x 128 dims), 2 per thread sharing the Wet column
    int dim = tid & 127;
    int nsBase = tid >> 7;                     // 0 or 1; partner node is nsBase+2
    float sb = sbt[dim], tbv = tb[dim];
    float wet0 = 0.f, wet1 = 0.f;
#pragma unroll 8
    for (int jj = 0; jj < 64; ++jj) {
        float wv = Wet[jj * 128 + dim];
        wet0 = fmaf(tsh[nsBase][jj], wv, wet0);
        wet1 = fmaf(tsh[nsBase + 2][jj], wv, wet1);
    }
#pragma unroll
    for (int r = 0; r < 2; ++r) {
        int ns = nsBase + r * 2;
        float wet = r ? wet1 : wet0;
        int nd = lb * 4 + ns;
        float outT = shO[ns][0][dim] + shO[ns][1][dim] + shO[ns][2][dim] + shO[ns][3][dim] + wet;
        float zt = zsh[ns][0] + zsh[ns][1] + zsh[ns][2] + zsh[ns][3] + SZB[nd];
        float beta = 1.f / (1.f + expf(-zt));
        float S = QB[(size_t)nd * QLD + dim];
        float a = beta * (S + sb) + (1.f - beta) * outT + tbv;
        xn[(size_t)nd * 128 + dim] = fmaxf(a, 0.f);
    }
}

// ---------------- batchnorm stats, float4-vectorized (G13) ----------------
// Thread t owns channels 4*(t&31)..+3 over row-phase t>>5; 4 phases combined in LDS,
// then one atomic pair per channel per block (same contention pattern as before).
__global__ void bn_stats_k(const float* __restrict__ x, int N, float* __restrict__ stats) {
    __shared__ float ps[4][128], pq[4][128];
    int t = threadIdx.x;                 // 128
    int rsub = t >> 5, ch4 = (t & 31) * 4;
    float s0 = 0.f, s1 = 0.f, s2 = 0.f, s3 = 0.f;
    float q0 = 0.f, q1 = 0.f, q2 = 0.f, q3 = 0.f;
    for (int n = blockIdx.x * 4 + rsub; n < N; n += gridDim.x * 4) {
        float4 v = *(const float4*)(x + (size_t)n * 128 + ch4);
        s0 += v.x; q0 = fmaf(v.x, v.x, q0);
        s1 += v.y; q1 = fmaf(v.y, v.y, q1);
        s2 += v.z; q2 = fmaf(v.z, v.z, q2);
        s3 += v.w; q3 = fmaf(v.w, v.w, q3);
    }
    ps[rsub][ch4] = s0; ps[rsub][ch4 + 1] = s1; ps[rsub][ch4 + 2] = s2; ps[rsub][ch4 + 3] = s3;
    pq[rsub][ch4] = q0; pq[rsub][ch4 + 1] = q1; pq[rsub][ch4 + 2] = q2; pq[rsub][ch4 + 3] = q3;
    __syncthreads();
    float S = (ps[0][t] + ps[1][t]) + (ps[2][t] + ps[3][t]);
    float Q = (pq[0][t] + pq[1][t]) + (pq[2][t] + pq[3][t]);
    atomicAdd(&stats[t], S);
    atomicAdd(&stats[128 + t], Q);
}

// bn apply + emit bf16 hi/lo split, float4-vectorized (bit-identical per element).
__global__ void bn_apply_k(const float* __restrict__ x, int N, const float* __restrict__ stats,
                           const float* __restrict__ g, const float* __restrict__ b,
                           unsigned short* __restrict__ Xhi, unsigned short* __restrict__ Xlo) {
    int i4 = blockIdx.x * 256 + threadIdx.x;     // float4 index
    if (i4 >= N * 32) return;
    int c4 = (i4 & 31) * 4;
    float4 v4 = ((const float4*)x)[i4];
    float vv[4] = {v4.x, v4.y, v4.z, v4.w};
    short4v hv, lv;
#pragma unroll
    for (int jj = 0; jj < 4; ++jj) {
        int c = c4 + jj;
        float m = stats[c] / (float)N;
        float var = fmaxf(stats[128 + c] / (float)N - m * m, 0.f);
        float inv = rsqrtf(var + 1e-5f);
        float v = g[c] * (vv[jj] - m) * inv + b[c];
        unsigned short h = f2bf(v);
        hv[jj] = (short)h;
        lv[jj] = (short)f2bf(v - bf2f(h));
    }
    *(short4v*)(Xhi + (size_t)i4 * 4) = hv;
    *(short4v*)(Xlo + (size_t)i4 * 4) = lv;
}

// bn apply + pooling score in one pass (wave = node). grid N/4, block 256.
__global__ void bn_apply_score_k(float* __restrict__ x, int N, const float* __restrict__ stats,
                                 const float* __restrict__ g, const float* __restrict__ b,
                                 const float* __restrict__ w, float* __restrict__ s) {
    int node = blockIdx.x * 4 + (threadIdx.x >> 6);
    int lane = threadIdx.x & 63;
    int c0 = lane, c1 = lane + 64;
    float m0 = stats[c0] / (float)N;
    float v0 = fmaxf(stats[128 + c0] / (float)N - m0 * m0, 0.f);
    float m1 = stats[c1] / (float)N;
    float v1 = fmaxf(stats[128 + c1] / (float)N - m1 * m1, 0.f);
    float* row = x + (size_t)node * 128;
    float x0 = g[c0] * (row[c0] - m0) * rsqrtf(v0 + 1e-5f) + b[c0];
    float x1 = g[c1] * (row[c1] - m1) * rsqrtf(v1 + 1e-5f) + b[c1];
    row[c0] = x0;
    row[c1] = x1;
    float w0 = w[c0], w1 = w[c1];
    float p  = x0 * w0 + x1 * w1;
    float nw = w0 * w0 + w1 * w1;
#pragma unroll
    for (int off = 32; off; off >>= 1) {
        p  += __shfl_xor(p, off, 64);
        nw += __shfl_xor(nw, off, 64);
    }
    if (lane == 0) s[node] = p / sqrtf(nw);
}

// ---------------- pool0: topk + readout + CSR rebuild + bf16 split ----------------
__global__ __launch_bounds__(128) void topk_pool0_k(
        const float* __restrict__ sc, const float* __restrict__ x,
        const int* __restrict__ src, const int* __restrict__ dst,
        float* __restrict__ rep,
        int* __restrict__ row_start, int* __restrict__ row_end,
        int* __restrict__ colb, int* __restrict__ eidb,
        unsigned short* __restrict__ Xhi, unsigned short* __restrict__ Xlo) {
    __shared__ float ls[128], th[64];
    __shared__ int lk[128], rk[128], oon[64];
    __shared__ int cnt[64], pref[64], cur[64];
    int g = blockIdx.x, t = threadIdx.x;
    float val = sc[g * 128 + t];
    ls[t] = val;
    __syncthreads();
    int c = 0;
    for (int j = 0; j < 128; ++j) {
        float vj = ls[j];
        c += (vj > val || (vj == val && j < t)) ? 1 : 0;
    }
    int kp = (c < 64) ? 1 : 0;
    lk[t] = kp;
    __syncthreads();
    int r = 0;
    for (int j = 0; j < t; ++j) r += lk[j];
    rk[t] = r;
    if (kp) { oon[r] = t; th[r] = tanhf(val); }
    __syncthreads();
    float mx = -INFINITY, sm = 0.f;
    for (int rr = 0; rr < 64; ++rr) {
        float v = x[(size_t)(g * 128 + oon[rr]) * 128 + t] * th[rr];
        int oidx = (g * 64 + rr) * 128 + t;
        unsigned short h = f2bf(v);
        Xhi[oidx] = h;
        Xlo[oidx] = f2bf(v - bf2f(h));
        mx = fmaxf(mx, v);
        sm += v;
    }
    rep[g * 256 + t] = mx;
    rep[g * 256 + 128 + t] = sm * (1.f / 64.f);
    if (t < 64) cnt[t] = 0;
    __syncthreads();
    int e0 = g * 512, nb = g * 128;
    int keepE[4], dr[4], sr[4];
#pragma unroll
    for (int i = 0; i < 4; ++i) {
        int e = e0 + t + i * 128;
        int s_ = src[e] - nb, d_ = dst[e] - nb;
        int ke = lk[s_] && lk[d_];
        keepE[i] = ke;
        dr[i] = rk[d_];
        sr[i] = rk[s_];
        if (ke) atomicAdd(&cnt[dr[i]], 1);
    }
    __syncthreads();
    if (t < 64) pref[t] = cnt[t];
    __syncthreads();
    for (int st = 1; st < 64; st <<= 1) {
        int v = (t < 64 && t >= st) ? pref[t - st] : 0;
        __syncthreads();
        if (t < 64) pref[t] += v;
        __syncthreads();
    }
    if (t < 64) {
        int ex = pref[t] - cnt[t];
        row_start[g * 64 + t] = e0 + ex;
        row_end[g * 64 + t]   = e0 + pref[t];
        cur[t] = ex;
    }
    __syncthreads();
#pragma unroll
    for (int i = 0; i < 4; ++i) {
        if (keepE[i]) {
            int pos = atomicAdd(&cur[dr[i]], 1);
            colb[e0 + pos] = g * 64 + sr[i];
            eidb[e0 + pos] = e0 + t + i * 128;
        }
    }
}

// ---------------- pool1: topk + readout only. n=64 -> k=32. block 128. ----------------------
__global__ __launch_bounds__(128) void topk_pool1_k(
        const float* __restrict__ sc, const float* __restrict__ x,
        float* __restrict__ rep) {
    __shared__ float ls[64], th[32];
    __shared__ int lk[64], oon[32];
    int g = blockIdx.x, t = threadIdx.x;
    float val = 0.f;
    if (t < 64) { val = sc[g * 64 + t]; ls[t] = val; }
    __syncthreads();
    if (t < 64) {
        int c = 0;
        for (int j = 0; j < 64; ++j) {
            float vj = ls[j];
            c += (vj > val || (vj == val && j < t)) ? 1 : 0;
        }
        int kp = (c < 32) ? 1 : 0;
        lk[t] = kp;
    }
    __syncthreads();
    if (t < 64 && lk[t]) {
        int r = 0;
        for (int j = 0; j < t; ++j) r += lk[j];
        oon[r] = t;
        th[r] = tanhf(val);
    }
    __syncthreads();
    float mx = -INFINITY, sm = 0.f;
    for (int rr = 0; rr < 32; ++rr) {
        float v = x[(size_t)(g * 64 + oon[rr]) * 128 + t] * th[rr];
        mx = fmaxf(mx, v);
        sm += v;
    }
    rep[g * 256 + t] = mx;
    rep[g * 256 + 128 + t] = sm * (1.f / 32.f);
}

// ---------------- MLP head: one block per graph, fp32 output ----------------
__global__ void head_k(const float* __restrict__ rep0, const float* __restrict__ rep1,
                       const float* __restrict__ W1, const float* __restrict__ b1,
                       const float* __restrict__ W2, const float* __restrict__ b2,
                       const float* __restrict__ W3, const float* __restrict__ b3,
                       float* __restrict__ out) {
    __shared__ float h[256], a1[256], a2[128], red[256];
    int g = blockIdx.x, t = threadIdx.x;  // 256
    h[t] = rep0[g * 256 + t] + rep1[g * 256 + t];
    __syncthreads();
    float acc = b1[t];
    for (int i = 0; i < 256; ++i) acc = fmaf(h[i], W1[i * 256 + t], acc);
    a1[t] = fmaxf(acc, 0.f);
    __syncthreads();
    if (t < 128) {
        float a = b2[t];
        for (int i = 0; i < 256; ++i) a = fmaf(a1[i], W2[i * 128 + t], a);
        a2[t] = fmaxf(a, 0.f);
    }
    __syncthreads();
    red[t] = (t < 128) ? a2[t] * W3[t] : 0.f;
    __syncthreads();
    for (int st = 128; st; st >>= 1) {
        if (t < st) red[t] += red[t + st];
        __syncthreads();
    }
    if (t == 0) out[g] = red[0] + b3[0];
}

// ======================================================================================
extern "C" void kernel_launch(void* const* d_in, const int* in_sizes, int n_in,
                              void* d_out, int out_size, void* d_ws, size_t ws_size,
                              hipStream_t stream) {
    (void)in_sizes; (void)n_in; (void)out_size; (void)ws_size;

    const float* x0    = (const float*)d_in[0];
    const int*   ei    = (const int*)d_in[1];
    const float* ea    = (const float*)d_in[2];
    const float* c1_Wq = (const float*)d_in[3];
    const float* c1_bq = (const float*)d_in[4];
    const float* c1_Wk = (const float*)d_in[5];
    const float* c1_bk = (const float*)d_in[6];
    const float* c1_Wv = (const float*)d_in[7];
    const float* c1_bv = (const float*)d_in[8];
    const float* c1_We = (const float*)d_in[9];
    const float* c1_Ws = (const float*)d_in[10];
    const float* c1_bs = (const float*)d_in[11];
    const float* c1_Wb = (const float*)d_in[12];
    const float* t1_W  = (const float*)d_in[13];
    const float* t1_b  = (const float*)d_in[14];
    const float* bn1_g = (const float*)d_in[15];
    const float* bn1_b = (const float*)d_in[16];
    const float* cl_Wq = (const float*)d_in[17];
    const float* cl_bq = (const float*)d_in[18];
    const float* cl_Wk = (const float*)d_in[19];
    const float* cl_bk = (const float*)d_in[20];
    const float* cl_Wv = (const float*)d_in[21];
    const float* cl_bv = (const float*)d_in[22];
    const float* cl_We = (const float*)d_in[23];
    const float* cl_Ws = (const float*)d_in[24];
    const float* cl_bs = (const float*)d_in[25];
    const float* cl_Wb = (const float*)d_in[26];
    const float* tl_W  = (const float*)d_in[27];
    const float* tl_b  = (const float*)d_in[28];
    const float* bnl_g = (const float*)d_in[29];
    const float* bnl_b = (const float*)d_in[30];
    const float* pool_w= (const float*)d_in[31];
    const float* l1_W  = (const float*)d_in[32];
    const float* l1_b  = (const float*)d_in[33];
    const float* l2_W  = (const float*)d_in[34];
    const float* l2_b  = (const float*)d_in[35];
    const float* l3_W  = (const float*)d_in[36];
    const float* l3_b  = (const float*)d_in[37];
    float* out = (float*)d_out;

    // -------- workspace layout (~138 MB) --------
    char* base = (char*)d_ws;
    size_t off = 0;
    auto alloc = [&](size_t bytes) -> void* {
        void* p = base + off;
        off += (bytes + 255) & ~(size_t)255;
        return p;
    };
    float* QB   = (float*)alloc((size_t)16384 * QLD * 4);   // 109 MB
    float* xA   = (float*)alloc((size_t)16384 * 128 * 4);
    float* xB   = (float*)alloc((size_t)16384 * 128 * 4);
    float* UB   = (float*)alloc((size_t)16384 * 64 * 4);
    float* VZB  = (float*)alloc((size_t)16384 * 4 * 4);
    float* SZB  = (float*)alloc((size_t)16384 * 4);
    float* stats  = (float*)alloc(256 * 4);
    float* scores = (float*)alloc(16384 * 4);
    float* rep0   = (float*)alloc(128 * 256 * 4);
    float* rep1   = (float*)alloc(128 * 256 * 4);
    int* row_start = (int*)alloc(16384 * 4);
    int* row_end   = (int*)alloc(16384 * 4);
    int* colb      = (int*)alloc(E_TOT * 4);
    int* eidb      = (int*)alloc(E_TOT * 4);
    unsigned short* Xhi = (unsigned short*)alloc((size_t)16384 * 128 * 2);  // 4.2 MB
    unsigned short* Xlo = (unsigned short*)alloc((size_t)16384 * 128 * 2);  // 4.2 MB

    // per-layer prep buffers
    LayerPrep P[3];
    const float* Wb_[3] = {c1_Wb, cl_Wb, cl_Wb + 1536};
    const float* Wk_[3] = {c1_Wk, cl_Wk, cl_Wk + 65536};
    for (int l = 0; l < 3; ++l) {
        LayerPrep& p = P[l];
        p.Wst  = (float*)alloc(128 * 128 * 4);
        p.ws_z = (float*)alloc(128 * 4);
        p.sbt  = (float*)alloc(128 * 4);
        p.zb   = (float*)alloc(16);
        p.Wu   = (float*)alloc(128 * 64 * 4);
        p.bu   = (float*)alloc(64 * 4);
        p.Wet  = (float*)alloc(64 * 128 * 4);
        p.wez  = (float*)alloc(64 * 4);
        p.Wvt  = (float*)alloc(128 * 512 * 4);
        p.bvt  = (float*)alloc(512 * 4);
        p.Wvz  = (float*)alloc(128 * 4 * 4);
        p.bvz  = (float*)alloc(16);
        p.Whi  = (unsigned short*)alloc((size_t)NCOL * 128 * 2);
        p.Wlo  = (unsigned short*)alloc((size_t)NCOL * 128 * 2);
    }
    P[0].Ws = c1_Ws; P[0].bs_ = c1_bs; P[0].Wq = c1_Wq; P[0].bq = c1_bq;
    P[0].We = c1_We; P[0].Wv = c1_Wv; P[0].bv = c1_bv; P[0].tW = t1_W; P[0].Fin = 64;
    P[1].Ws = cl_Ws; P[1].bs_ = cl_bs; P[1].Wq = cl_Wq; P[1].bq = cl_bq;
    P[1].We = cl_We; P[1].Wv = cl_Wv; P[1].bv = cl_bv; P[1].tW = tl_W; P[1].Fin = 128;
    P[2].Ws = cl_Ws + 65536; P[2].bs_ = cl_bs + 512; P[2].Wq = cl_Wq + 65536;
    P[2].bq = cl_bq + 512; P[2].We = cl_We + 8192; P[2].Wv = cl_Wv + 65536;
    P[2].bv = cl_bv + 512; P[2].tW = tl_W + 65536; P[2].Fin = 128;

    // ---- all weight prep up front, 3 layers wide (activation-independent) ----
    {
        int unitsMax = (10 * 128 + 138) + (69 * 128 + 133);
        prep_all_k<<<dim3((unitsMax + 3) / 4, 3), 256, 0, stream>>>(P[0], P[1], P[2],
                                                                    Wb_[0], Wb_[1], Wb_[2]);
        wsplit_all_k<<<dim3((NCOL * 128 + 255) / 256, 3), 256, 0, stream>>>(P[0], P[1], P[2],
                                                                            Wk_[0], Wk_[1], Wk_[2]);
    }

    // ---- CSR over original edges + input split ----
    csr_graph_k<<<B_G, 128, 0, stream>>>(ei, ei + E_TOT, row_start, row_end, colb, eidb);
    xsplit_k<<<(16384 * 64 / 4 + 255) / 256, 256, 0, stream>>>(x0, 16384 * 64 / 4, Xhi, Xlo);

    auto tconv = [&](int L, int N, const float* bq, const float* bk, const float* tb,
                     float* xn) {
        int nwg8 = 28 * (N / 128) / 8;
        if (P[L].Fin == 64)
            qkvs_mfma<64><<<dim3(28, N / 128), 256, 0, stream>>>(Xhi, Xlo, P[L].Whi, P[L].Wlo,
                                                                 bq, bk, P[L].bvt, P[L].bu,
                                                                 P[L].bvz, P[L].zb,
                                                                 QB, UB, VZB, SZB, nwg8);
        else
            qkvs_mfma<128><<<dim3(28, N / 128), 256, 0, stream>>>(Xhi, Xlo, P[L].Whi, P[L].Wlo,
                                                                  bq, bk, P[L].bvt, P[L].bu,
                                                                  P[L].bvz, P[L].zb,
                                                                  QB, UB, VZB, SZB, nwg8);
        attn_combine_k<<<N / 4, 256, 0, stream>>>(QB, UB, VZB, SZB,
                                                  row_start, row_end, colb, eidb,
                                                  ea, P[L].wez, P[L].Wet, P[L].sbt, tb,
                                                  xn, N / 32, stats);
    };

    // ---- layer 1: tconv(Fin=64) + t1 + bn1 ----
    tconv(0, 16384, c1_bq, c1_bk, t1_b, xA);
    bn_stats_k<<<512, 128, 0, stream>>>(xA, 16384, stats);
    bn_apply_k<<<(16384 * 32 + 255) / 256, 256, 0, stream>>>(xA, 16384, stats, bn1_g, bn1_b,
                                                             Xhi, Xlo);

    // ---- loop layer 0 (Fin=128, N=16384) ----
    tconv(1, 16384, cl_bq, cl_bk, tl_b, xB);
    bn_stats_k<<<512, 128, 0, stream>>>(xB, 16384, stats);
    bn_apply_score_k<<<16384 / 4, 256, 0, stream>>>(xB, 16384, stats, bnl_g, bnl_b,
                                                    pool_w, scores);

    // ---- pool 0 (fused topk+readout+CSR+split) ----
    topk_pool0_k<<<B_G, 128, 0, stream>>>(scores, xB, ei, ei + E_TOT, rep0,
                                          row_start, row_end, colb, eidb, Xhi, Xlo);

    // ---- loop layer 1 (Fin=128, N=8192) ----
    tconv(2, 8192, cl_bq + 512, cl_bk + 512, tl_b + 128, xB);
    bn_stats_k<<<512, 128, 0, stream>>>(xB, 8192, stats);
    bn_apply_score_k<<<8192 / 4, 256, 0, stream>>>(xB, 8192, stats, bnl_g + 128, bnl_b + 128,
                                                   pool_w + 128, scores);

    // ---- pool 1 (fused topk+readout) ----
    topk_pool1_k<<<B_G, 128, 0, stream>>>(scores, xB, rep1);

    // ---- MLP head (fp32 out) ----
    head_k<<<B_G, 256, 0, stream>>>(rep0, rep1, l1_W, l1_b, l2_W, l2_b, l3_W, l3_b, out);
}